// Round 5
// baseline (1660.628 us; speedup 1.0000x reference)
//
#include <hip/hip_runtime.h>
#include <math.h>

#define B_ 8
#define N_ 20000
#define E_ 40000
#define H_ 128
#define L_ 4
#define A_ 4
#define TS 132    // fp32 LDS row stride (k_out2)
#define ERS 264   // fp16 LDS row stride, edge kernel (256+8)
#define NRS 136   // fp16 LDS row stride, node kernel (128+8)
#define EPB2 128  // edges per block
#define NPB2 128  // nodes per block

typedef _Float16 f16x8 __attribute__((ext_vector_type(8)));
typedef _Float16 f16x4v __attribute__((ext_vector_type(4)));
typedef float f32x4 __attribute__((ext_vector_type(4)));

__device__ __forceinline__ float silu_f(float x) { return x / (1.f + __expf(-x)); }

// ---------------- setup kernels ----------------

__global__ void k_zero(int* __restrict__ deg, int* __restrict__ cursor) {
    int i = blockIdx.x * 256 + threadIdx.x;
    if (i < N_) { deg[i] = 0; cursor[i] = 0; }
}

__global__ void k_deg(const int* __restrict__ bond, int* __restrict__ deg) {
    int e = blockIdx.x * 256 + threadIdx.x;
    if (e < E_) {
        atomicAdd(&deg[bond[2 * e]], 1);
        atomicAdd(&deg[bond[2 * e + 1]], 1);
    }
}

__global__ void k_scan(const int* __restrict__ deg, int* __restrict__ indptr) {
    __shared__ int sums[1024];
    const int CH = (N_ + 1023) / 1024;  // 20
    int t = threadIdx.x;
    int s0 = t * CH;
    int s1 = min(s0 + CH, N_);
    int s = 0;
    for (int i = s0; i < s1; ++i) s += deg[i];
    sums[t] = s;
    __syncthreads();
    for (int off = 1; off < 1024; off <<= 1) {
        int v = (t >= off) ? sums[t - off] : 0;
        __syncthreads();
        sums[t] += v;
        __syncthreads();
    }
    int base = (t > 0) ? sums[t - 1] : 0;
    int run = base;
    for (int i = s0; i < s1; ++i) { indptr[i] = run; run += deg[i]; }
    if (s1 == N_ && s0 < N_) indptr[N_] = run;
}

__global__ void k_fill(const int* __restrict__ bond, const int* __restrict__ indptr,
                       int* __restrict__ cursor, int* __restrict__ adj) {
    int e = blockIdx.x * 256 + threadIdx.x;
    if (e < E_) {
        int s = bond[2 * e], d = bond[2 * e + 1];
        int ps = indptr[s] + atomicAdd(&cursor[s], 1);
        adj[ps] = (e << 1);        // node is src -> sign -
        int pd = indptr[d] + atomicAdd(&cursor[d], 1);
        adj[pd] = (e << 1) | 1;    // node is dst -> sign +
    }
}

// Convert W[K][128] fp32 -> B-fragment-layout fp16 for mfma_f32_16x16x32_f16:
// Wf[((kt*8 + nt)*64 + lane)*8 + j] = W[kt*32 + (lane>>4)*8 + j][nt*16 + (lane&15)]
__global__ void k_wprep(const float* __restrict__ W, _Float16* __restrict__ Wf, int K) {
    int idx = blockIdx.x * 256 + threadIdx.x;
    if (idx >= K * 128) return;
    int j = idx & 7, lane = (idx >> 3) & 63, nt = (idx >> 9) & 7, kt = idx >> 12;
    int k = kt * 32 + (lane >> 4) * 8 + j;
    int n = nt * 16 + (lane & 15);
    Wf[idx] = (_Float16)W[k * 128 + n];
}

__global__ void k_temb(const float* __restrict__ tv,
                       const float* __restrict__ W1, const float* __restrict__ b1,
                       const float* __restrict__ W2, const float* __restrict__ b2,
                       float* __restrict__ t_emb) {
    __shared__ float te[64];
    __shared__ float h1[128];
    int b = blockIdx.x;
    int tid = threadIdx.x;
    float tval = tv[b];
    if (tid < 32) {
        float fr = __expf((float)tid * (-logf(10000.f) / 31.f));
        float a = tval * fr;
        te[tid] = sinf(a);
        te[tid + 32] = cosf(a);
    }
    __syncthreads();
    float acc = b1[tid];
    for (int k = 0; k < 64; ++k) acc += te[k] * W1[k * 128 + tid];
    h1[tid] = silu_f(acc);
    __syncthreads();
    float acc2 = b2[tid];
    for (int k = 0; k < 128; ++k) acc2 += h1[k] * W2[k * 128 + tid];
    t_emb[b * 128 + tid] = acc2;
}

__global__ void k_embproj(const float* __restrict__ emb, const float* __restrict__ W,
                          const float* __restrict__ bias, float* __restrict__ outp) {
    int tid = threadIdx.x;       // 512 threads
    int a = tid >> 7, j = tid & 127;
    float acc = bias[j];
    for (int k = 0; k < 128; ++k) acc += emb[a * 128 + k] * W[k * 128 + j];
    outp[a * 128 + j] = acc;
}

__global__ void k_hinit(const int* __restrict__ at, const float* __restrict__ embp,
                        const float* __restrict__ temb, float* __restrict__ h,
                        _Float16* __restrict__ h16) {
    size_t idx4 = (size_t)blockIdx.x * 256 + threadIdx.x;   // over B*N*H/4
    size_t e0 = idx4 * 4;
    int j = (int)(e0 % H_);
    size_t bn = e0 / H_;
    int n = (int)(bn % N_);
    int b = (int)(bn / N_);
    int a = at[n];
    float4 ep = *(const float4*)(embp + a * H_ + j);
    float4 tv = *(const float4*)(temb + b * H_ + j);
    float4 r = make_float4(ep.x + tv.x, ep.y + tv.y, ep.z + tv.z, ep.w + tv.w);
    ((float4*)h)[idx4] = r;
    f16x4v o;
    o[0] = (_Float16)r.x; o[1] = (_Float16)r.y; o[2] = (_Float16)r.z; o[3] = (_Float16)r.w;
    *(f16x4v*)(h16 + e0) = o;
}

__global__ void k_xcopy(const float* __restrict__ x, float* __restrict__ xb) {
    int i = blockIdx.x * 256 + threadIdx.x;  // 480000 exact
    xb[i] = x[i];
}

// ---------------- MFMA GEMM core (2 row-tiles per wave) ----------------
// Asw: wave's 32 rows in LDS fp16 (row stride RS). Wf: frag-layout fp16.
// acc[rt][nt] covers C rows rt*16+quad*4+r, col nt*16+ml.
template <int RS, int KT>
__device__ __forceinline__ void mfma_gemm2(const _Float16* Asw, const _Float16* __restrict__ Wf,
                                           f32x4 (&acc)[2][8], int ml, int quad, int lane) {
    #pragma unroll
    for (int kt = 0; kt < KT; ++kt) {
        f16x8 a0 = *(const f16x8*)(Asw + ml * RS + kt * 32 + quad * 8);
        f16x8 a1 = *(const f16x8*)(Asw + (16 + ml) * RS + kt * 32 + quad * 8);
        #pragma unroll
        for (int nt = 0; nt < 8; ++nt) {
            f16x8 b = *(const f16x8*)(Wf + (((kt * 8 + nt) * 64 + lane) * 8));
            acc[0][nt] = __builtin_amdgcn_mfma_f32_16x16x32_f16(a0, b, acc[0][nt], 0, 0, 0);
            acc[1][nt] = __builtin_amdgcn_mfma_f32_16x16x32_f16(a1, b, acc[1][nt], 0, 0, 0);
        }
    }
}

// ---------------- fp32 tiled GEMM (k_out2 only) ----------------
template <int STRIDE, int K>
__device__ __forceinline__ void gemm_t(const float* As, const float* __restrict__ W,
                                       float (&acc)[4][8], int r4, int c) {
    const float4* Wv = (const float4*)W;
    #pragma unroll 2
    for (int k = 0; k < K; k += 4) {
        float a[4][4];
        #pragma unroll
        for (int i = 0; i < 4; ++i)
            *(float4*)a[i] = *(const float4*)(As + (r4 + i) * STRIDE + k);
        #pragma unroll
        for (int kk = 0; kk < 4; ++kk) {
            float4 w0 = Wv[(k + kk) * 32 + c * 2];
            float4 w1 = Wv[(k + kk) * 32 + c * 2 + 1];
            #pragma unroll
            for (int i = 0; i < 4; ++i) {
                float av = a[i][kk];
                acc[i][0] += av * w0.x; acc[i][1] += av * w0.y;
                acc[i][2] += av * w0.z; acc[i][3] += av * w0.w;
                acc[i][4] += av * w1.x; acc[i][5] += av * w1.y;
                acc[i][6] += av * w1.z; acc[i][7] += av * w1.w;
            }
        }
    }
}

__device__ __forceinline__ void bias_init(float (&acc)[4][8], const float* __restrict__ bias, int c) {
    float4 b0 = ((const float4*)bias)[c * 2];
    float4 b1 = ((const float4*)bias)[c * 2 + 1];
    #pragma unroll
    for (int i = 0; i < 4; ++i) {
        acc[i][0] = b0.x; acc[i][1] = b0.y; acc[i][2] = b0.z; acc[i][3] = b0.w;
        acc[i][4] = b1.x; acc[i][5] = b1.y; acc[i][6] = b1.z; acc[i][7] = b1.w;
    }
}

// ---------------- per-layer kernels ----------------

// 128 edges/block, 4 waves x 32 rows (2 row-tiles share each B-fragment).
__global__ __launch_bounds__(256) void k_edge_mfma(
    const _Float16* __restrict__ h16, const float* __restrict__ xcur,
    const int* __restrict__ bond,
    const float* __restrict__ Wm1, const float* __restrict__ bm1,
    const _Float16* __restrict__ Wm1f,
    const float* __restrict__ bm2, const _Float16* __restrict__ Wm2f,
    const float* __restrict__ bc1, const _Float16* __restrict__ Wc1f,
    const float* __restrict__ Wc2,
    _Float16* __restrict__ m16, float* __restrict__ cw_out) {
    __shared__ _Float16 As[EPB2 * ERS];   // 67584 B
    __shared__ float ds_s[EPB2];
    int tid = threadIdx.x;
    size_t be0 = (size_t)blockIdx.x * EPB2;
    {
        int el = tid >> 1, q = tid & 1;
        int be = blockIdx.x * EPB2 + el;
        int b = be / E_, e = be - b * E_;
        int s = bond[2 * e], d = bond[2 * e + 1];
        const _Float16* hs = h16 + ((size_t)b * N_ + s) * H_;
        const _Float16* hd = h16 + ((size_t)b * N_ + d) * H_;
        #pragma unroll
        for (int j = 0; j < 8; ++j) {
            int c = q * 8 + j;
            *(f16x8*)(As + el * ERS + c * 8) = *(const f16x8*)(hs + c * 8);
            *(f16x8*)(As + el * ERS + 128 + c * 8) = *(const f16x8*)(hd + c * 8);
        }
        if (q == 0) {
            const float* xs = xcur + ((size_t)b * N_ + s) * 3;
            const float* xd = xcur + ((size_t)b * N_ + d) * 3;
            float dx = xd[0] - xs[0], dy = xd[1] - xs[1], dz = xd[2] - xs[2];
            ds_s[el] = sqrtf(dx * dx + dy * dy + dz * dz);
        }
    }
    __syncthreads();

    int lane = tid & 63, w = tid >> 6;
    int ml = lane & 15, quad = lane >> 4;
    _Float16* Asw = As + w * 32 * ERS;
    const float* wd = Wm1 + 256 * H_;

    f32x4 acc[2][8];
    // ---- GEMM1: acc = bm1 + dist*wd + [h_s|h_d] @ Wm1[0:256]
    #pragma unroll
    for (int nt = 0; nt < 8; ++nt) {
        int col = nt * 16 + ml;
        float bb = bm1[col];
        float ww = wd[col];
        #pragma unroll
        for (int rt = 0; rt < 2; ++rt)
            #pragma unroll
            for (int r = 0; r < 4; ++r) {
                float di = ds_s[w * 32 + rt * 16 + quad * 4 + r];
                acc[rt][nt][r] = bb + di * ww;
            }
    }
    mfma_gemm2<ERS, 8>(Asw, Wm1f, acc, ml, quad, lane);
    __syncthreads();
    // silu -> m1 -> LDS cols 0..127
    #pragma unroll
    for (int rt = 0; rt < 2; ++rt)
        #pragma unroll
        for (int nt = 0; nt < 8; ++nt)
            #pragma unroll
            for (int r = 0; r < 4; ++r)
                Asw[(rt * 16 + quad * 4 + r) * ERS + nt * 16 + ml] = (_Float16)silu_f(acc[rt][nt][r]);
    __syncthreads();

    // ---- GEMM2: m = silu(m1 @ Wm2 + bm2)
    #pragma unroll
    for (int nt = 0; nt < 8; ++nt) {
        float bb = bm2[nt * 16 + ml];
        #pragma unroll
        for (int rt = 0; rt < 2; ++rt)
            #pragma unroll
            for (int r = 0; r < 4; ++r) acc[rt][nt][r] = bb;
    }
    mfma_gemm2<ERS, 4>(Asw, Wm2f, acc, ml, quad, lane);
    __syncthreads();
    #pragma unroll
    for (int rt = 0; rt < 2; ++rt)
        #pragma unroll
        for (int nt = 0; nt < 8; ++nt)
            #pragma unroll
            for (int r = 0; r < 4; ++r)
                Asw[(rt * 16 + quad * 4 + r) * ERS + 128 + nt * 16 + ml] = (_Float16)silu_f(acc[rt][nt][r]);
    __syncthreads();
    // vectorized coalesced m16 store from LDS
    {
        int el = tid >> 1, q = tid & 1;
        #pragma unroll
        for (int j = 0; j < 8; ++j) {
            int c = q * 8 + j;
            *(f16x8*)(m16 + (be0 + el) * H_ + c * 8) = *(const f16x8*)(As + el * ERS + 128 + c * 8);
        }
    }

    // ---- GEMM3: cw = silu(m @ Wc1 + bc1) @ Wc2
    #pragma unroll
    for (int nt = 0; nt < 8; ++nt) {
        float bb = bc1[nt * 16 + ml];
        #pragma unroll
        for (int rt = 0; rt < 2; ++rt)
            #pragma unroll
            for (int r = 0; r < 4; ++r) acc[rt][nt][r] = bb;
    }
    mfma_gemm2<ERS, 4>(Asw + 128, Wc1f, acc, ml, quad, lane);
    float part[2][4] = {{0.f, 0.f, 0.f, 0.f}, {0.f, 0.f, 0.f, 0.f}};
    #pragma unroll
    for (int nt = 0; nt < 8; ++nt) {
        float wv = Wc2[nt * 16 + ml];
        #pragma unroll
        for (int rt = 0; rt < 2; ++rt)
            #pragma unroll
            for (int r = 0; r < 4; ++r) part[rt][r] += silu_f(acc[rt][nt][r]) * wv;
    }
    #pragma unroll
    for (int off = 1; off < 16; off <<= 1)
        #pragma unroll
        for (int rt = 0; rt < 2; ++rt)
            #pragma unroll
            for (int r = 0; r < 4; ++r) part[rt][r] += __shfl_xor(part[rt][r], off, 64);
    if (ml == 0) {
        #pragma unroll
        for (int rt = 0; rt < 2; ++rt)
            #pragma unroll
            for (int r = 0; r < 4; ++r)
                cw_out[be0 + w * 32 + rt * 16 + quad * 4 + r] = part[rt][r];
    }
}

__global__ void k_coord(const float* __restrict__ xcur, float* __restrict__ xnext,
                        const float* __restrict__ cw, const int* __restrict__ bond,
                        const int* __restrict__ indptr, const int* __restrict__ adj) {
    int idx = blockIdx.x * 256 + threadIdx.x;   // B*N exact
    int b = idx / N_;
    int n = idx - b * N_;
    const float* xb = xcur + (size_t)b * N_ * 3;
    int p0 = indptr[n], p1 = indptr[n + 1];
    float ax = 0.f, ay = 0.f, az = 0.f;
    for (int p = p0; p < p1; ++p) {
        int a = adj[p];
        int e = a >> 1;
        float sgn = (a & 1) ? 1.f : -1.f;
        int s = bond[2 * e], d = bond[2 * e + 1];
        float dx = xb[d * 3 + 0] - xb[s * 3 + 0];
        float dy = xb[d * 3 + 1] - xb[s * 3 + 1];
        float dz = xb[d * 3 + 2] - xb[s * 3 + 2];
        float dist = sqrtf(dx * dx + dy * dy + dz * dz);
        float w = cw[(size_t)b * E_ + e] * sgn / (dist + 1e-8f);
        ax += dx * w; ay += dy * w; az += dz * w;
    }
    float cnt = (float)max(p1 - p0, 1);
    xnext[(size_t)idx * 3 + 0] = xb[n * 3 + 0] + ax / cnt;
    xnext[(size_t)idx * 3 + 1] = xb[n * 3 + 1] + ay / cnt;
    xnext[(size_t)idx * 3 + 2] = xb[n * 3 + 2] + az / cnt;
}

// 128 nodes/block: u = silu(h@Wn1a + agg@Wn1b + bn1); h += u@Wn2 + bn2
__global__ __launch_bounds__(256) void k_node_mfma(
    float* __restrict__ h, _Float16* __restrict__ h16,
    const _Float16* __restrict__ m16,
    const int* __restrict__ indptr, const int* __restrict__ adj,
    const float* __restrict__ bn1, const _Float16* __restrict__ Wn1f,
    const float* __restrict__ bn2, const _Float16* __restrict__ Wn2f) {
    __shared__ _Float16 As[NPB2 * NRS];   // 34816 B
    int tid = threadIdx.x;
    size_t be0 = (size_t)blockIdx.x * NPB2;
    int el = tid >> 1, q = tid & 1;
    int be = blockIdx.x * NPB2 + el;   // b*N + n
    int b = be / N_, n = be - b * N_;
    // stage h tile (fp16)
    {
        const _Float16* hr = h16 + (size_t)be * H_;
        #pragma unroll
        for (int j = 0; j < 8; ++j) {
            int c = q * 8 + j;
            *(f16x8*)(As + el * NRS + c * 8) = *(const f16x8*)(hr + c * 8);
        }
    }
    __syncthreads();

    int lane = tid & 63, w = tid >> 6;
    int ml = lane & 15, quad = lane >> 4;
    _Float16* Asw = As + w * 32 * NRS;

    f32x4 acc[2][8];
    #pragma unroll
    for (int nt = 0; nt < 8; ++nt) {
        float bb = bn1[nt * 16 + ml];
        #pragma unroll
        for (int rt = 0; rt < 2; ++rt)
            #pragma unroll
            for (int r = 0; r < 4; ++r) acc[rt][nt][r] = bb;
    }
    mfma_gemm2<NRS, 4>(Asw, Wn1f, acc, ml, quad, lane);     // + h @ Wn1a
    __syncthreads();
    // agg gather -> As (overwrites h tile); two 32-col passes to cap registers
    {
        int p0 = indptr[n], p1 = indptr[n + 1];
        #pragma unroll
        for (int pp = 0; pp < 2; ++pp) {
            float ag[32];
            #pragma unroll
            for (int i = 0; i < 32; ++i) ag[i] = 0.f;
            for (int p = p0; p < p1; ++p) {
                int e = adj[p] >> 1;
                const _Float16* mp = m16 + ((size_t)b * E_ + e) * H_ + q * 64 + pp * 32;
                #pragma unroll
                for (int j = 0; j < 4; ++j) {
                    f16x8 v = *(const f16x8*)(mp + j * 8);
                    #pragma unroll
                    for (int i = 0; i < 8; ++i) ag[j * 8 + i] += (float)v[i];
                }
            }
            #pragma unroll
            for (int j = 0; j < 4; ++j) {
                f16x8 o;
                #pragma unroll
                for (int i = 0; i < 8; ++i) o[i] = (_Float16)ag[j * 8 + i];
                *(f16x8*)(As + el * NRS + q * 64 + pp * 32 + j * 8) = o;
            }
        }
    }
    __syncthreads();
    mfma_gemm2<NRS, 4>(Asw, Wn1f + 4 * 8 * 64 * 8, acc, ml, quad, lane);  // + agg @ Wn1b
    __syncthreads();
    // u -> As
    #pragma unroll
    for (int rt = 0; rt < 2; ++rt)
        #pragma unroll
        for (int nt = 0; nt < 8; ++nt)
            #pragma unroll
            for (int r = 0; r < 4; ++r)
                Asw[(rt * 16 + quad * 4 + r) * NRS + nt * 16 + ml] = (_Float16)silu_f(acc[rt][nt][r]);
    __syncthreads();
    f32x4 acc2[2][8];
    #pragma unroll
    for (int nt = 0; nt < 8; ++nt) {
        float bb = bn2[nt * 16 + ml];
        #pragma unroll
        for (int rt = 0; rt < 2; ++rt)
            #pragma unroll
            for (int r = 0; r < 4; ++r) acc2[rt][nt][r] = bb;
    }
    mfma_gemm2<NRS, 4>(Asw, Wn2f, acc2, ml, quad, lane);
    // residual (fp32 h) + writeback h and h16
    #pragma unroll
    for (int rt = 0; rt < 2; ++rt)
        #pragma unroll
        for (int nt = 0; nt < 8; ++nt)
            #pragma unroll
            for (int r = 0; r < 4; ++r) {
                int row = w * 32 + rt * 16 + quad * 4 + r;
                size_t g = (size_t)(be0 + row) * H_ + nt * 16 + ml;
                float v = h[g] + acc2[rt][nt][r];
                h[g] = v;
                h16[g] = (_Float16)v;
            }
}

// out = silu(h@Wo1+bo1)@Wo2 + bo2 + (xfin - xorig)
__global__ __launch_bounds__(256) void k_out2(
    const float* __restrict__ h, const float* __restrict__ xfin, const float* __restrict__ xorig,
    const float* __restrict__ Wo1, const float* __restrict__ bo1,
    const float* __restrict__ Wo2, const float* __restrict__ bo2,
    float* __restrict__ out) {
    __shared__ float As[64 * TS];
    __shared__ float red[64 * 48];
    int tid = threadIdx.x;
    {
        int nl = tid >> 2, q = tid & 3;
        size_t row = (size_t)blockIdx.x * 64 + nl;
        const float4* hr = (const float4*)(h + row * H_);
        #pragma unroll
        for (int j = 0; j < 8; ++j) {
            int f4 = j * 4 + q;
            *(float4*)(As + nl * TS + f4 * 4) = hr[f4];
        }
    }
    __syncthreads();
    int r4 = (tid >> 4) * 4, c = tid & 15;
    float acc[4][8];
    bias_init(acc, bo1, c);
    gemm_t<TS, 128>(As, Wo1, acc, r4, c);
    #pragma unroll
    for (int i = 0; i < 4; ++i) {
        float p0 = 0.f, p1 = 0.f, p2 = 0.f;
        #pragma unroll
        for (int j = 0; j < 8; ++j) {
            float u = silu_f(acc[i][j]);
            int col = c * 8 + j;
            p0 += u * Wo2[col * 3 + 0];
            p1 += u * Wo2[col * 3 + 1];
            p2 += u * Wo2[col * 3 + 2];
        }
        red[(r4 + i) * 48 + c * 3 + 0] = p0;
        red[(r4 + i) * 48 + c * 3 + 1] = p1;
        red[(r4 + i) * 48 + c * 3 + 2] = p2;
    }
    __syncthreads();
    if (tid < 192) {
        int row = tid / 3, jj = tid - row * 3;
        float s = 0.f;
        #pragma unroll
        for (int cc = 0; cc < 16; ++cc) s += red[row * 48 + cc * 3 + jj];
        size_t grow = (size_t)blockIdx.x * 64 + row;
        out[grow * 3 + jj] = s + bo2[jj] + xfin[grow * 3 + jj] - xorig[grow * 3 + jj];
    }
}

// ---------------- launcher ----------------

extern "C" void kernel_launch(void* const* d_in, const int* in_sizes, int n_in,
                              void* d_out, int out_size, void* d_ws, size_t ws_size,
                              hipStream_t stream) {
    const float* x = (const float*)d_in[0];
    const float* t = (const float*)d_in[1];
    const int* atom_types = (const int*)d_in[2];
    const int* bond = (const int*)d_in[3];
    const float* emb_table = (const float*)d_in[4];
    const float* W_t1 = (const float*)d_in[5];
    const float* b_t1 = (const float*)d_in[6];
    const float* W_t2 = (const float*)d_in[7];
    const float* b_t2 = (const float*)d_in[8];
    const float* W_node = (const float*)d_in[9];
    const float* b_node = (const float*)d_in[10];
    const float* Wm1 = (const float*)d_in[11];
    const float* bm1 = (const float*)d_in[12];
    const float* Wm2 = (const float*)d_in[13];
    const float* bm2 = (const float*)d_in[14];
    const float* Wn1 = (const float*)d_in[15];
    const float* bn1 = (const float*)d_in[16];
    const float* Wn2 = (const float*)d_in[17];
    const float* bn2 = (const float*)d_in[18];
    const float* Wc1 = (const float*)d_in[19];
    const float* bc1 = (const float*)d_in[20];
    const float* Wc2 = (const float*)d_in[21];
    const float* W_o1 = (const float*)d_in[22];
    const float* b_o1 = (const float*)d_in[23];
    const float* W_o2 = (const float*)d_in[24];
    const float* b_o2 = (const float*)d_in[25];
    float* out = (float*)d_out;

    char* p = (char*)d_ws;
    auto alloc = [&](size_t bytes) -> void* {
        void* r = (void*)p;
        p += (bytes + 255) & ~(size_t)255;
        return r;
    };
    // ~211 MB total (R1's 252 MB layout fit; R2's 415 MB overflowed)
    float* t_emb = (float*)alloc((size_t)B_ * H_ * 4);
    float* emb_proj = (float*)alloc((size_t)A_ * H_ * 4);
    int* deg = (int*)alloc((size_t)N_ * 4);
    int* indptr = (int*)alloc((size_t)(N_ + 1) * 4);
    int* cursor = (int*)alloc((size_t)N_ * 4);
    int* adj = (int*)alloc((size_t)2 * E_ * 4);
    float* xb0 = (float*)alloc((size_t)B_ * N_ * 3 * 4);
    float* xb1 = (float*)alloc((size_t)B_ * N_ * 3 * 4);
    float* cw = (float*)alloc((size_t)B_ * E_ * 4);
    float* h = (float*)alloc((size_t)B_ * N_ * H_ * 4);
    _Float16* h16 = (_Float16*)alloc((size_t)B_ * N_ * H_ * 2);
    _Float16* m16 = (_Float16*)alloc((size_t)B_ * E_ * H_ * 2);
    _Float16* Wm1f = (_Float16*)alloc((size_t)L_ * 256 * H_ * 2);
    _Float16* Wm2f = (_Float16*)alloc((size_t)L_ * H_ * H_ * 2);
    _Float16* Wc1f = (_Float16*)alloc((size_t)L_ * H_ * H_ * 2);
    _Float16* Wn1f = (_Float16*)alloc((size_t)L_ * 256 * H_ * 2);
    _Float16* Wn2f = (_Float16*)alloc((size_t)L_ * H_ * H_ * 2);

    k_zero<<<(N_ + 255) / 256, 256, 0, stream>>>(deg, cursor);
    k_deg<<<(E_ + 255) / 256, 256, 0, stream>>>(bond, deg);
    k_scan<<<1, 1024, 0, stream>>>(deg, indptr);
    k_fill<<<(E_ + 255) / 256, 256, 0, stream>>>(bond, indptr, cursor, adj);
    k_temb<<<B_, 128, 0, stream>>>(t, W_t1, b_t1, W_t2, b_t2, t_emb);
    k_embproj<<<1, 512, 0, stream>>>(emb_table, W_node, b_node, emb_proj);
    k_hinit<<<(B_ * N_ * H_ / 4) / 256, 256, 0, stream>>>(atom_types, emb_proj, t_emb, h, h16);
    k_xcopy<<<(B_ * N_ * 3) / 256, 256, 0, stream>>>(x, xb0);
    for (int l = 0; l < L_; ++l) {
        k_wprep<<<128, 256, 0, stream>>>(Wm1 + (size_t)l * 257 * H_, Wm1f + (size_t)l * 256 * H_, 256);
        k_wprep<<<64, 256, 0, stream>>>(Wm2 + (size_t)l * H_ * H_, Wm2f + (size_t)l * H_ * H_, 128);
        k_wprep<<<64, 256, 0, stream>>>(Wc1 + (size_t)l * H_ * H_, Wc1f + (size_t)l * H_ * H_, 128);
        k_wprep<<<128, 256, 0, stream>>>(Wn1 + (size_t)l * 2 * H_ * H_, Wn1f + (size_t)l * 256 * H_, 256);
        k_wprep<<<64, 256, 0, stream>>>(Wn2 + (size_t)l * H_ * H_, Wn2f + (size_t)l * H_ * H_, 128);
    }

    float* xc = xb0;
    float* xn = xb1;
    for (int l = 0; l < L_; ++l) {
        k_edge_mfma<<<(B_ * E_) / EPB2, 256, 0, stream>>>(
            h16, xc, bond,
            Wm1 + (size_t)l * 257 * H_, bm1 + l * H_, Wm1f + (size_t)l * 256 * H_,
            bm2 + l * H_, Wm2f + (size_t)l * H_ * H_,
            bc1 + l * H_, Wc1f + (size_t)l * H_ * H_,
            Wc2 + (size_t)l * H_, m16, cw);
        k_coord<<<(B_ * N_) / 256, 256, 0, stream>>>(xc, xn, cw, bond, indptr, adj);
        k_node_mfma<<<(B_ * N_) / NPB2, 256, 0, stream>>>(
            h, h16, m16, indptr, adj,
            bn1 + l * H_, Wn1f + (size_t)l * 256 * H_,
            bn2 + l * H_, Wn2f + (size_t)l * H_ * H_);
        float* tmp = xc; xc = xn; xn = tmp;
    }
    k_out2<<<(B_ * N_) / 64, 256, 0, stream>>>(h, xc, x, W_o1, b_o1, W_o2, b_o2, out);
}

// Round 6
// 1282.297 us; speedup vs baseline: 1.2950x; 1.2950x over previous
//
#include <hip/hip_runtime.h>
#include <math.h>

#define B_ 8
#define N_ 20000
#define E_ 40000
#define H_ 128
#define L_ 4
#define A_ 4
#define TS 132    // fp32 LDS row stride (k_out2)
#define ERS 264   // fp16 LDS row stride, edge kernel (256+8)
#define NRS 136   // fp16 LDS row stride, node kernel (128+8)
#define EPB2 128  // edges per block (edge kernel)
#define NPB 64    // nodes per block (node kernel) — R4 structure

typedef _Float16 f16x8 __attribute__((ext_vector_type(8)));
typedef _Float16 f16x4v __attribute__((ext_vector_type(4)));
typedef float f32x4 __attribute__((ext_vector_type(4)));

__device__ __forceinline__ float silu_f(float x) { return x / (1.f + __expf(-x)); }

// ---------------- setup kernels ----------------

__global__ void k_zero(int* __restrict__ deg, int* __restrict__ cursor) {
    int i = blockIdx.x * 256 + threadIdx.x;
    if (i < N_) { deg[i] = 0; cursor[i] = 0; }
}

__global__ void k_deg(const int* __restrict__ bond, int* __restrict__ deg) {
    int e = blockIdx.x * 256 + threadIdx.x;
    if (e < E_) {
        atomicAdd(&deg[bond[2 * e]], 1);
        atomicAdd(&deg[bond[2 * e + 1]], 1);
    }
}

__global__ void k_scan(const int* __restrict__ deg, int* __restrict__ indptr) {
    __shared__ int sums[1024];
    const int CH = (N_ + 1023) / 1024;  // 20
    int t = threadIdx.x;
    int s0 = t * CH;
    int s1 = min(s0 + CH, N_);
    int s = 0;
    for (int i = s0; i < s1; ++i) s += deg[i];
    sums[t] = s;
    __syncthreads();
    for (int off = 1; off < 1024; off <<= 1) {
        int v = (t >= off) ? sums[t - off] : 0;
        __syncthreads();
        sums[t] += v;
        __syncthreads();
    }
    int base = (t > 0) ? sums[t - 1] : 0;
    int run = base;
    for (int i = s0; i < s1; ++i) { indptr[i] = run; run += deg[i]; }
    if (s1 == N_ && s0 < N_) indptr[N_] = run;
}

__global__ void k_fill(const int* __restrict__ bond, const int* __restrict__ indptr,
                       int* __restrict__ cursor, int* __restrict__ adj) {
    int e = blockIdx.x * 256 + threadIdx.x;
    if (e < E_) {
        int s = bond[2 * e], d = bond[2 * e + 1];
        int ps = indptr[s] + atomicAdd(&cursor[s], 1);
        adj[ps] = (e << 1);        // node is src -> sign -
        int pd = indptr[d] + atomicAdd(&cursor[d], 1);
        adj[pd] = (e << 1) | 1;    // node is dst -> sign +
    }
}

// Convert W[K][128] fp32 -> B-fragment-layout fp16 for mfma_f32_16x16x32_f16.
// blockIdx.y = layer; strides passed per weight type.
__global__ void k_wprepL(const float* __restrict__ W, _Float16* __restrict__ Wf,
                         int K, int wstride) {
    int l = blockIdx.y;
    const float* Wl = W + (size_t)l * wstride;
    _Float16* Wfl = Wf + (size_t)l * K * 128;
    int idx = blockIdx.x * 256 + threadIdx.x;
    if (idx >= K * 128) return;
    int j = idx & 7, lane = (idx >> 3) & 63, nt = (idx >> 9) & 7, kt = idx >> 12;
    int k = kt * 32 + (lane >> 4) * 8 + j;
    int n = nt * 16 + (lane & 15);
    Wfl[idx] = (_Float16)Wl[k * 128 + n];
}

__global__ void k_temb(const float* __restrict__ tv,
                       const float* __restrict__ W1, const float* __restrict__ b1,
                       const float* __restrict__ W2, const float* __restrict__ b2,
                       float* __restrict__ t_emb) {
    __shared__ float te[64];
    __shared__ float h1[128];
    int b = blockIdx.x;
    int tid = threadIdx.x;
    float tval = tv[b];
    if (tid < 32) {
        float fr = __expf((float)tid * (-logf(10000.f) / 31.f));
        float a = tval * fr;
        te[tid] = sinf(a);
        te[tid + 32] = cosf(a);
    }
    __syncthreads();
    float acc = b1[tid];
    for (int k = 0; k < 64; ++k) acc += te[k] * W1[k * 128 + tid];
    h1[tid] = silu_f(acc);
    __syncthreads();
    float acc2 = b2[tid];
    for (int k = 0; k < 128; ++k) acc2 += h1[k] * W2[k * 128 + tid];
    t_emb[b * 128 + tid] = acc2;
}

__global__ void k_embproj(const float* __restrict__ emb, const float* __restrict__ W,
                          const float* __restrict__ bias, float* __restrict__ outp) {
    int tid = threadIdx.x;       // 512 threads
    int a = tid >> 7, j = tid & 127;
    float acc = bias[j];
    for (int k = 0; k < 128; ++k) acc += emb[a * 128 + k] * W[k * 128 + j];
    outp[a * 128 + j] = acc;
}

__global__ void k_hinit(const int* __restrict__ at, const float* __restrict__ embp,
                        const float* __restrict__ temb, float* __restrict__ h,
                        _Float16* __restrict__ h16) {
    size_t idx4 = (size_t)blockIdx.x * 256 + threadIdx.x;   // over B*N*H/4
    size_t e0 = idx4 * 4;
    int j = (int)(e0 % H_);
    size_t bn = e0 / H_;
    int n = (int)(bn % N_);
    int b = (int)(bn / N_);
    int a = at[n];
    float4 ep = *(const float4*)(embp + a * H_ + j);
    float4 tv = *(const float4*)(temb + b * H_ + j);
    float4 r = make_float4(ep.x + tv.x, ep.y + tv.y, ep.z + tv.z, ep.w + tv.w);
    ((float4*)h)[idx4] = r;
    f16x4v o;
    o[0] = (_Float16)r.x; o[1] = (_Float16)r.y; o[2] = (_Float16)r.z; o[3] = (_Float16)r.w;
    *(f16x4v*)(h16 + e0) = o;
}

__global__ void k_xcopy(const float* __restrict__ x, float* __restrict__ xb) {
    int i = blockIdx.x * 256 + threadIdx.x;  // 480000 exact
    xb[i] = x[i];
}

// ---------------- MFMA GEMM cores ----------------
// Single row-tile (16 rows/wave):
template <int RS, int KT>
__device__ __forceinline__ void mfma_gemm(const _Float16* Asw, const _Float16* __restrict__ Wf,
                                          f32x4 (&acc)[8], int ml, int quad, int lane) {
    #pragma unroll
    for (int kt = 0; kt < KT; ++kt) {
        f16x8 a = *(const f16x8*)(Asw + ml * RS + kt * 32 + quad * 8);
        #pragma unroll
        for (int nt = 0; nt < 8; ++nt) {
            f16x8 b = *(const f16x8*)(Wf + (((kt * 8 + nt) * 64 + lane) * 8));
            acc[nt] = __builtin_amdgcn_mfma_f32_16x16x32_f16(a, b, acc[nt], 0, 0, 0);
        }
    }
}

// Two row-tiles (32 rows/wave) sharing each B fragment:
template <int RS, int KT>
__device__ __forceinline__ void mfma_gemm2(const _Float16* Asw, const _Float16* __restrict__ Wf,
                                           f32x4 (&acc)[2][8], int ml, int quad, int lane) {
    #pragma unroll
    for (int kt = 0; kt < KT; ++kt) {
        f16x8 a0 = *(const f16x8*)(Asw + ml * RS + kt * 32 + quad * 8);
        f16x8 a1 = *(const f16x8*)(Asw + (16 + ml) * RS + kt * 32 + quad * 8);
        #pragma unroll
        for (int nt = 0; nt < 8; ++nt) {
            f16x8 b = *(const f16x8*)(Wf + (((kt * 8 + nt) * 64 + lane) * 8));
            acc[0][nt] = __builtin_amdgcn_mfma_f32_16x16x32_f16(a0, b, acc[0][nt], 0, 0, 0);
            acc[1][nt] = __builtin_amdgcn_mfma_f32_16x16x32_f16(a1, b, acc[1][nt], 0, 0, 0);
        }
    }
}

// ---------------- fp32 tiled GEMM (k_out2 only) ----------------
template <int STRIDE, int K>
__device__ __forceinline__ void gemm_t(const float* As, const float* __restrict__ W,
                                       float (&acc)[4][8], int r4, int c) {
    const float4* Wv = (const float4*)W;
    #pragma unroll 2
    for (int k = 0; k < K; k += 4) {
        float a[4][4];
        #pragma unroll
        for (int i = 0; i < 4; ++i)
            *(float4*)a[i] = *(const float4*)(As + (r4 + i) * STRIDE + k);
        #pragma unroll
        for (int kk = 0; kk < 4; ++kk) {
            float4 w0 = Wv[(k + kk) * 32 + c * 2];
            float4 w1 = Wv[(k + kk) * 32 + c * 2 + 1];
            #pragma unroll
            for (int i = 0; i < 4; ++i) {
                float av = a[i][kk];
                acc[i][0] += av * w0.x; acc[i][1] += av * w0.y;
                acc[i][2] += av * w0.z; acc[i][3] += av * w0.w;
                acc[i][4] += av * w1.x; acc[i][5] += av * w1.y;
                acc[i][6] += av * w1.z; acc[i][7] += av * w1.w;
            }
        }
    }
}

__device__ __forceinline__ void bias_init(float (&acc)[4][8], const float* __restrict__ bias, int c) {
    float4 b0 = ((const float4*)bias)[c * 2];
    float4 b1 = ((const float4*)bias)[c * 2 + 1];
    #pragma unroll
    for (int i = 0; i < 4; ++i) {
        acc[i][0] = b0.x; acc[i][1] = b0.y; acc[i][2] = b0.z; acc[i][3] = b0.w;
        acc[i][4] = b1.x; acc[i][5] = b1.y; acc[i][6] = b1.z; acc[i][7] = b1.w;
    }
}

// ---------------- per-layer kernels ----------------

// 128 edges/block, 4 waves x 32 rows (2 row-tiles share each B-fragment).
__global__ __launch_bounds__(256) void k_edge_mfma(
    const _Float16* __restrict__ h16, const float* __restrict__ xcur,
    const int* __restrict__ bond,
    const float* __restrict__ Wm1, const float* __restrict__ bm1,
    const _Float16* __restrict__ Wm1f,
    const float* __restrict__ bm2, const _Float16* __restrict__ Wm2f,
    const float* __restrict__ bc1, const _Float16* __restrict__ Wc1f,
    const float* __restrict__ Wc2,
    _Float16* __restrict__ m16, float* __restrict__ cw_out) {
    __shared__ _Float16 As[EPB2 * ERS];   // 67584 B
    __shared__ float ds_s[EPB2];
    int tid = threadIdx.x;
    size_t be0 = (size_t)blockIdx.x * EPB2;
    {
        int el = tid >> 1, q = tid & 1;
        int be = blockIdx.x * EPB2 + el;
        int b = be / E_, e = be - b * E_;
        int s = bond[2 * e], d = bond[2 * e + 1];
        const _Float16* hs = h16 + ((size_t)b * N_ + s) * H_;
        const _Float16* hd = h16 + ((size_t)b * N_ + d) * H_;
        #pragma unroll
        for (int j = 0; j < 8; ++j) {
            int c = q * 8 + j;
            *(f16x8*)(As + el * ERS + c * 8) = *(const f16x8*)(hs + c * 8);
            *(f16x8*)(As + el * ERS + 128 + c * 8) = *(const f16x8*)(hd + c * 8);
        }
        if (q == 0) {
            const float* xs = xcur + ((size_t)b * N_ + s) * 3;
            const float* xd = xcur + ((size_t)b * N_ + d) * 3;
            float dx = xd[0] - xs[0], dy = xd[1] - xs[1], dz = xd[2] - xs[2];
            ds_s[el] = sqrtf(dx * dx + dy * dy + dz * dz);
        }
    }
    __syncthreads();

    int lane = tid & 63, w = tid >> 6;
    int ml = lane & 15, quad = lane >> 4;
    _Float16* Asw = As + w * 32 * ERS;
    const float* wd = Wm1 + 256 * H_;

    f32x4 acc[2][8];
    // ---- GEMM1: acc = bm1 + dist*wd + [h_s|h_d] @ Wm1[0:256]
    #pragma unroll
    for (int nt = 0; nt < 8; ++nt) {
        int col = nt * 16 + ml;
        float bb = bm1[col];
        float ww = wd[col];
        #pragma unroll
        for (int rt = 0; rt < 2; ++rt)
            #pragma unroll
            for (int r = 0; r < 4; ++r) {
                float di = ds_s[w * 32 + rt * 16 + quad * 4 + r];
                acc[rt][nt][r] = bb + di * ww;
            }
    }
    mfma_gemm2<ERS, 8>(Asw, Wm1f, acc, ml, quad, lane);
    __syncthreads();
    // silu -> m1 -> LDS cols 0..127
    #pragma unroll
    for (int rt = 0; rt < 2; ++rt)
        #pragma unroll
        for (int nt = 0; nt < 8; ++nt)
            #pragma unroll
            for (int r = 0; r < 4; ++r)
                Asw[(rt * 16 + quad * 4 + r) * ERS + nt * 16 + ml] = (_Float16)silu_f(acc[rt][nt][r]);
    __syncthreads();

    // ---- GEMM2: m = silu(m1 @ Wm2 + bm2)
    #pragma unroll
    for (int nt = 0; nt < 8; ++nt) {
        float bb = bm2[nt * 16 + ml];
        #pragma unroll
        for (int rt = 0; rt < 2; ++rt)
            #pragma unroll
            for (int r = 0; r < 4; ++r) acc[rt][nt][r] = bb;
    }
    mfma_gemm2<ERS, 4>(Asw, Wm2f, acc, ml, quad, lane);
    __syncthreads();
    #pragma unroll
    for (int rt = 0; rt < 2; ++rt)
        #pragma unroll
        for (int nt = 0; nt < 8; ++nt)
            #pragma unroll
            for (int r = 0; r < 4; ++r)
                Asw[(rt * 16 + quad * 4 + r) * ERS + 128 + nt * 16 + ml] = (_Float16)silu_f(acc[rt][nt][r]);
    __syncthreads();
    // vectorized coalesced m16 store from LDS
    {
        int el = tid >> 1, q = tid & 1;
        #pragma unroll
        for (int j = 0; j < 8; ++j) {
            int c = q * 8 + j;
            *(f16x8*)(m16 + (be0 + el) * H_ + c * 8) = *(const f16x8*)(As + el * ERS + 128 + c * 8);
        }
    }

    // ---- GEMM3: cw = silu(m @ Wc1 + bc1) @ Wc2
    #pragma unroll
    for (int nt = 0; nt < 8; ++nt) {
        float bb = bc1[nt * 16 + ml];
        #pragma unroll
        for (int rt = 0; rt < 2; ++rt)
            #pragma unroll
            for (int r = 0; r < 4; ++r) acc[rt][nt][r] = bb;
    }
    mfma_gemm2<ERS, 4>(Asw + 128, Wc1f, acc, ml, quad, lane);
    float part[2][4] = {{0.f, 0.f, 0.f, 0.f}, {0.f, 0.f, 0.f, 0.f}};
    #pragma unroll
    for (int nt = 0; nt < 8; ++nt) {
        float wv = Wc2[nt * 16 + ml];
        #pragma unroll
        for (int rt = 0; rt < 2; ++rt)
            #pragma unroll
            for (int r = 0; r < 4; ++r) part[rt][r] += silu_f(acc[rt][nt][r]) * wv;
    }
    #pragma unroll
    for (int off = 1; off < 16; off <<= 1)
        #pragma unroll
        for (int rt = 0; rt < 2; ++rt)
            #pragma unroll
            for (int r = 0; r < 4; ++r) part[rt][r] += __shfl_xor(part[rt][r], off, 64);
    if (ml == 0) {
        #pragma unroll
        for (int rt = 0; rt < 2; ++rt)
            #pragma unroll
            for (int r = 0; r < 4; ++r)
                cw_out[be0 + w * 32 + rt * 16 + quad * 4 + r] = part[rt][r];
    }
}

__global__ void k_coord(const float* __restrict__ xcur, float* __restrict__ xnext,
                        const float* __restrict__ cw, const int* __restrict__ bond,
                        const int* __restrict__ indptr, const int* __restrict__ adj) {
    int idx = blockIdx.x * 256 + threadIdx.x;   // B*N exact
    int b = idx / N_;
    int n = idx - b * N_;
    const float* xb = xcur + (size_t)b * N_ * 3;
    int p0 = indptr[n], p1 = indptr[n + 1];
    float ax = 0.f, ay = 0.f, az = 0.f;
    for (int p = p0; p < p1; ++p) {
        int a = adj[p];
        int e = a >> 1;
        float sgn = (a & 1) ? 1.f : -1.f;
        int s = bond[2 * e], d = bond[2 * e + 1];
        float dx = xb[d * 3 + 0] - xb[s * 3 + 0];
        float dy = xb[d * 3 + 1] - xb[s * 3 + 1];
        float dz = xb[d * 3 + 2] - xb[s * 3 + 2];
        float dist = sqrtf(dx * dx + dy * dy + dz * dz);
        float w = cw[(size_t)b * E_ + e] * sgn / (dist + 1e-8f);
        ax += dx * w; ay += dy * w; az += dz * w;
    }
    float cnt = (float)max(p1 - p0, 1);
    xnext[(size_t)idx * 3 + 0] = xb[n * 3 + 0] + ax / cnt;
    xnext[(size_t)idx * 3 + 1] = xb[n * 3 + 1] + ay / cnt;
    xnext[(size_t)idx * 3 + 2] = xb[n * 3 + 2] + az / cnt;
}

// 64 nodes/block (R4 structure): u = silu(h@Wn1a + agg@Wn1b + bn1); h += u@Wn2 + bn2
__global__ __launch_bounds__(256) void k_node_mfma(
    float* __restrict__ h, _Float16* __restrict__ h16,
    const _Float16* __restrict__ m16,
    const int* __restrict__ indptr, const int* __restrict__ adj,
    const float* __restrict__ bn1, const _Float16* __restrict__ Wn1f,
    const float* __restrict__ bn2, const _Float16* __restrict__ Wn2f) {
    __shared__ _Float16 As[NPB * NRS];   // 17408 B
    int tid = threadIdx.x;
    int el = tid >> 2, q = tid & 3;
    int be = blockIdx.x * NPB + el;   // b*N + n
    int b = be / N_, n = be - b * N_;
    // stage h tile (fp16)
    {
        const _Float16* hr = h16 + (size_t)be * H_;
        #pragma unroll
        for (int j = 0; j < 4; ++j) {
            int c = q + 4 * j;
            *(f16x8*)(As + el * NRS + c * 8) = *(const f16x8*)(hr + c * 8);
        }
    }
    __syncthreads();

    int lane = tid & 63, w = tid >> 6;
    int ml = lane & 15, quad = lane >> 4;
    _Float16* Asw = As + w * 16 * NRS;
    size_t be0 = (size_t)blockIdx.x * NPB;

    f32x4 acc[8];
    #pragma unroll
    for (int nt = 0; nt < 8; ++nt) {
        float bb = bn1[nt * 16 + ml];
        #pragma unroll
        for (int r = 0; r < 4; ++r) acc[nt][r] = bb;
    }
    mfma_gemm<NRS, 4>(Asw, Wn1f, acc, ml, quad, lane);     // + h @ Wn1a
    __syncthreads();
    // agg gather -> As (overwrites h tile); 4 threads/row, 32 cols each, one pass
    {
        float ag[4][8];
        #pragma unroll
        for (int j = 0; j < 4; ++j)
            #pragma unroll
            for (int i = 0; i < 8; ++i) ag[j][i] = 0.f;
        int p0 = indptr[n], p1 = indptr[n + 1];
        for (int p = p0; p < p1; ++p) {
            int e = adj[p] >> 1;
            const _Float16* mp = m16 + ((size_t)b * E_ + e) * H_;
            #pragma unroll
            for (int j = 0; j < 4; ++j) {
                f16x8 v = *(const f16x8*)(mp + (q + 4 * j) * 8);
                #pragma unroll
                for (int i = 0; i < 8; ++i) ag[j][i] += (float)v[i];
            }
        }
        #pragma unroll
        for (int j = 0; j < 4; ++j) {
            f16x8 o;
            #pragma unroll
            for (int i = 0; i < 8; ++i) o[i] = (_Float16)ag[j][i];
            *(f16x8*)(As + el * NRS + (q + 4 * j) * 8) = o;
        }
    }
    __syncthreads();
    mfma_gemm<NRS, 4>(Asw, Wn1f + 4 * 8 * 64 * 8, acc, ml, quad, lane);  // + agg @ Wn1b
    __syncthreads();
    // u -> As
    #pragma unroll
    for (int nt = 0; nt < 8; ++nt)
        #pragma unroll
        for (int r = 0; r < 4; ++r)
            Asw[(quad * 4 + r) * NRS + nt * 16 + ml] = (_Float16)silu_f(acc[nt][r]);
    __syncthreads();
    f32x4 acc2[8];
    #pragma unroll
    for (int nt = 0; nt < 8; ++nt) {
        float bb = bn2[nt * 16 + ml];
        #pragma unroll
        for (int r = 0; r < 4; ++r) acc2[nt][r] = bb;
    }
    mfma_gemm<NRS, 4>(Asw, Wn2f, acc2, ml, quad, lane);
    // residual (fp32 h) + writeback h and h16
    #pragma unroll
    for (int nt = 0; nt < 8; ++nt)
        #pragma unroll
        for (int r = 0; r < 4; ++r) {
            int row = w * 16 + quad * 4 + r;
            size_t g = (size_t)(be0 + row) * H_ + nt * 16 + ml;
            float v = h[g] + acc2[nt][r];
            h[g] = v;
            h16[g] = (_Float16)v;
        }
}

// out = silu(h@Wo1+bo1)@Wo2 + bo2 + (xfin - xorig)
__global__ __launch_bounds__(256) void k_out2(
    const float* __restrict__ h, const float* __restrict__ xfin, const float* __restrict__ xorig,
    const float* __restrict__ Wo1, const float* __restrict__ bo1,
    const float* __restrict__ Wo2, const float* __restrict__ bo2,
    float* __restrict__ out) {
    __shared__ float As[64 * TS];
    __shared__ float red[64 * 48];
    int tid = threadIdx.x;
    {
        int nl = tid >> 2, q = tid & 3;
        size_t row = (size_t)blockIdx.x * 64 + nl;
        const float4* hr = (const float4*)(h + row * H_);
        #pragma unroll
        for (int j = 0; j < 8; ++j) {
            int f4 = j * 4 + q;
            *(float4*)(As + nl * TS + f4 * 4) = hr[f4];
        }
    }
    __syncthreads();
    int r4 = (tid >> 4) * 4, c = tid & 15;
    float acc[4][8];
    bias_init(acc, bo1, c);
    gemm_t<TS, 128>(As, Wo1, acc, r4, c);
    #pragma unroll
    for (int i = 0; i < 4; ++i) {
        float p0 = 0.f, p1 = 0.f, p2 = 0.f;
        #pragma unroll
        for (int j = 0; j < 8; ++j) {
            float u = silu_f(acc[i][j]);
            int col = c * 8 + j;
            p0 += u * Wo2[col * 3 + 0];
            p1 += u * Wo2[col * 3 + 1];
            p2 += u * Wo2[col * 3 + 2];
        }
        red[(r4 + i) * 48 + c * 3 + 0] = p0;
        red[(r4 + i) * 48 + c * 3 + 1] = p1;
        red[(r4 + i) * 48 + c * 3 + 2] = p2;
    }
    __syncthreads();
    if (tid < 192) {
        int row = tid / 3, jj = tid - row * 3;
        float s = 0.f;
        #pragma unroll
        for (int cc = 0; cc < 16; ++cc) s += red[row * 48 + cc * 3 + jj];
        size_t grow = (size_t)blockIdx.x * 64 + row;
        out[grow * 3 + jj] = s + bo2[jj] + xfin[grow * 3 + jj] - xorig[grow * 3 + jj];
    }
}

// ---------------- launcher ----------------

extern "C" void kernel_launch(void* const* d_in, const int* in_sizes, int n_in,
                              void* d_out, int out_size, void* d_ws, size_t ws_size,
                              hipStream_t stream) {
    const float* x = (const float*)d_in[0];
    const float* t = (const float*)d_in[1];
    const int* atom_types = (const int*)d_in[2];
    const int* bond = (const int*)d_in[3];
    const float* emb_table = (const float*)d_in[4];
    const float* W_t1 = (const float*)d_in[5];
    const float* b_t1 = (const float*)d_in[6];
    const float* W_t2 = (const float*)d_in[7];
    const float* b_t2 = (const float*)d_in[8];
    const float* W_node = (const float*)d_in[9];
    const float* b_node = (const float*)d_in[10];
    const float* Wm1 = (const float*)d_in[11];
    const float* bm1 = (const float*)d_in[12];
    const float* Wm2 = (const float*)d_in[13];
    const float* bm2 = (const float*)d_in[14];
    const float* Wn1 = (const float*)d_in[15];
    const float* bn1 = (const float*)d_in[16];
    const float* Wn2 = (const float*)d_in[17];
    const float* bn2 = (const float*)d_in[18];
    const float* Wc1 = (const float*)d_in[19];
    const float* bc1 = (const float*)d_in[20];
    const float* Wc2 = (const float*)d_in[21];
    const float* W_o1 = (const float*)d_in[22];
    const float* b_o1 = (const float*)d_in[23];
    const float* W_o2 = (const float*)d_in[24];
    const float* b_o2 = (const float*)d_in[25];
    float* out = (float*)d_out;

    char* p = (char*)d_ws;
    auto alloc = [&](size_t bytes) -> void* {
        void* r = (void*)p;
        p += (bytes + 255) & ~(size_t)255;
        return r;
    };
    // ~211 MB total (R1's 252 MB layout fit; R2's 415 MB overflowed)
    float* t_emb = (float*)alloc((size_t)B_ * H_ * 4);
    float* emb_proj = (float*)alloc((size_t)A_ * H_ * 4);
    int* deg = (int*)alloc((size_t)N_ * 4);
    int* indptr = (int*)alloc((size_t)(N_ + 1) * 4);
    int* cursor = (int*)alloc((size_t)N_ * 4);
    int* adj = (int*)alloc((size_t)2 * E_ * 4);
    float* xb0 = (float*)alloc((size_t)B_ * N_ * 3 * 4);
    float* xb1 = (float*)alloc((size_t)B_ * N_ * 3 * 4);
    float* cw = (float*)alloc((size_t)B_ * E_ * 4);
    float* h = (float*)alloc((size_t)B_ * N_ * H_ * 4);
    _Float16* h16 = (_Float16*)alloc((size_t)B_ * N_ * H_ * 2);
    _Float16* m16 = (_Float16*)alloc((size_t)B_ * E_ * H_ * 2);
    _Float16* Wm1f = (_Float16*)alloc((size_t)L_ * 256 * H_ * 2);
    _Float16* Wm2f = (_Float16*)alloc((size_t)L_ * H_ * H_ * 2);
    _Float16* Wc1f = (_Float16*)alloc((size_t)L_ * H_ * H_ * 2);
    _Float16* Wn1f = (_Float16*)alloc((size_t)L_ * 256 * H_ * 2);
    _Float16* Wn2f = (_Float16*)alloc((size_t)L_ * H_ * H_ * 2);

    k_zero<<<(N_ + 255) / 256, 256, 0, stream>>>(deg, cursor);
    k_deg<<<(E_ + 255) / 256, 256, 0, stream>>>(bond, deg);
    k_scan<<<1, 1024, 0, stream>>>(deg, indptr);
    k_fill<<<(E_ + 255) / 256, 256, 0, stream>>>(bond, indptr, cursor, adj);
    k_temb<<<B_, 128, 0, stream>>>(t, W_t1, b_t1, W_t2, b_t2, t_emb);
    k_embproj<<<1, 512, 0, stream>>>(emb_table, W_node, b_node, emb_proj);
    k_hinit<<<(B_ * N_ * H_ / 4) / 256, 256, 0, stream>>>(atom_types, emb_proj, t_emb, h, h16);
    k_xcopy<<<(B_ * N_ * 3) / 256, 256, 0, stream>>>(x, xb0);
    // weight prep: one launch per weight type, layer via blockIdx.y
    k_wprepL<<<dim3(128, L_), 256, 0, stream>>>(Wm1, Wm1f, 256, 257 * H_);
    k_wprepL<<<dim3(64, L_), 256, 0, stream>>>(Wm2, Wm2f, 128, H_ * H_);
    k_wprepL<<<dim3(64, L_), 256, 0, stream>>>(Wc1, Wc1f, 128, H_ * H_);
    k_wprepL<<<dim3(128, L_), 256, 0, stream>>>(Wn1, Wn1f, 256, 2 * H_ * H_);
    k_wprepL<<<dim3(64, L_), 256, 0, stream>>>(Wn2, Wn2f, 128, H_ * H_);

    float* xc = xb0;
    float* xn = xb1;
    for (int l = 0; l < L_; ++l) {
        k_edge_mfma<<<(B_ * E_) / EPB2, 256, 0, stream>>>(
            h16, xc, bond,
            Wm1 + (size_t)l * 257 * H_, bm1 + l * H_, Wm1f + (size_t)l * 256 * H_,
            bm2 + l * H_, Wm2f + (size_t)l * H_ * H_,
            bc1 + l * H_, Wc1f + (size_t)l * H_ * H_,
            Wc2 + (size_t)l * H_, m16, cw);
        k_coord<<<(B_ * N_) / 256, 256, 0, stream>>>(xc, xn, cw, bond, indptr, adj);
        k_node_mfma<<<(B_ * N_) / NPB, 256, 0, stream>>>(
            h, h16, m16, indptr, adj,
            bn1 + l * H_, Wn1f + (size_t)l * 256 * H_,
            bn2 + l * H_, Wn2f + (size_t)l * H_ * H_);
        float* tmp = xc; xc = xn; xn = tmp;
    }
    k_out2<<<(B_ * N_) / 64, 256, 0, stream>>>(h, xc, x, W_o1, b_o1, W_o2, b_o2, out);
}

// Round 7
// 1194.960 us; speedup vs baseline: 1.3897x; 1.0731x over previous
//
#include <hip/hip_runtime.h>
#include <math.h>

#define B_ 8
#define N_ 20000
#define E_ 40000
#define H_ 128
#define L_ 4
#define A_ 4
#define TS 132    // fp32 LDS row stride (k_out2)
#define MRS 136   // fp16 LDS row stride (128+8), edge + node kernels
#define EPB 64    // edges per block
#define NPB 64    // nodes per block

// compiler-only memory fence: orders LDS ops across phases without s_barrier
#define WFENCE __asm__ __volatile__("" ::: "memory")

typedef _Float16 f16x8 __attribute__((ext_vector_type(8)));
typedef _Float16 f16x4v __attribute__((ext_vector_type(4)));
typedef float f32x4 __attribute__((ext_vector_type(4)));

__device__ __forceinline__ float silu_f(float x) { return x / (1.f + __expf(-x)); }

// ---------------- setup kernels ----------------

__global__ void k_zero(int* __restrict__ deg, int* __restrict__ cursor) {
    int i = blockIdx.x * 256 + threadIdx.x;
    if (i < N_) { deg[i] = 0; cursor[i] = 0; }
}

__global__ void k_deg(const int* __restrict__ bond, int* __restrict__ deg) {
    int e = blockIdx.x * 256 + threadIdx.x;
    if (e < E_) {
        atomicAdd(&deg[bond[2 * e]], 1);
        atomicAdd(&deg[bond[2 * e + 1]], 1);
    }
}

__global__ void k_scan(const int* __restrict__ deg, int* __restrict__ indptr) {
    __shared__ int sums[1024];
    const int CH = (N_ + 1023) / 1024;  // 20
    int t = threadIdx.x;
    int s0 = t * CH;
    int s1 = min(s0 + CH, N_);
    int s = 0;
    for (int i = s0; i < s1; ++i) s += deg[i];
    sums[t] = s;
    __syncthreads();
    for (int off = 1; off < 1024; off <<= 1) {
        int v = (t >= off) ? sums[t - off] : 0;
        __syncthreads();
        sums[t] += v;
        __syncthreads();
    }
    int base = (t > 0) ? sums[t - 1] : 0;
    int run = base;
    for (int i = s0; i < s1; ++i) { indptr[i] = run; run += deg[i]; }
    if (s1 == N_ && s0 < N_) indptr[N_] = run;
}

__global__ void k_fill(const int* __restrict__ bond, const int* __restrict__ indptr,
                       int* __restrict__ cursor, int* __restrict__ adj) {
    int e = blockIdx.x * 256 + threadIdx.x;
    if (e < E_) {
        int s = bond[2 * e], d = bond[2 * e + 1];
        int ps = indptr[s] + atomicAdd(&cursor[s], 1);
        adj[ps] = (e << 1);        // node is src -> sign -
        int pd = indptr[d] + atomicAdd(&cursor[d], 1);
        adj[pd] = (e << 1) | 1;    // node is dst -> sign +
    }
}

// Convert W[K][128] fp32 -> B-fragment-layout fp16 for mfma_f32_16x16x32_f16.
// blockIdx.y = layer; strides passed per weight type.
__global__ void k_wprepL(const float* __restrict__ W, _Float16* __restrict__ Wf,
                         int K, int wstride) {
    int l = blockIdx.y;
    const float* Wl = W + (size_t)l * wstride;
    _Float16* Wfl = Wf + (size_t)l * K * 128;
    int idx = blockIdx.x * 256 + threadIdx.x;
    if (idx >= K * 128) return;
    int j = idx & 7, lane = (idx >> 3) & 63, nt = (idx >> 9) & 7, kt = idx >> 12;
    int k = kt * 32 + (lane >> 4) * 8 + j;
    int n = nt * 16 + (lane & 15);
    Wfl[idx] = (_Float16)Wl[k * 128 + n];
}

__global__ void k_temb(const float* __restrict__ tv,
                       const float* __restrict__ W1, const float* __restrict__ b1,
                       const float* __restrict__ W2, const float* __restrict__ b2,
                       float* __restrict__ t_emb) {
    __shared__ float te[64];
    __shared__ float h1[128];
    int b = blockIdx.x;
    int tid = threadIdx.x;
    float tval = tv[b];
    if (tid < 32) {
        float fr = __expf((float)tid * (-logf(10000.f) / 31.f));
        float a = tval * fr;
        te[tid] = sinf(a);
        te[tid + 32] = cosf(a);
    }
    __syncthreads();
    float acc = b1[tid];
    for (int k = 0; k < 64; ++k) acc += te[k] * W1[k * 128 + tid];
    h1[tid] = silu_f(acc);
    __syncthreads();
    float acc2 = b2[tid];
    for (int k = 0; k < 128; ++k) acc2 += h1[k] * W2[k * 128 + tid];
    t_emb[b * 128 + tid] = acc2;
}

__global__ void k_embproj(const float* __restrict__ emb, const float* __restrict__ W,
                          const float* __restrict__ bias, float* __restrict__ outp) {
    int tid = threadIdx.x;       // 512 threads
    int a = tid >> 7, j = tid & 127;
    float acc = bias[j];
    for (int k = 0; k < 128; ++k) acc += emb[a * 128 + k] * W[k * 128 + j];
    outp[a * 128 + j] = acc;
}

__global__ void k_hinit(const int* __restrict__ at, const float* __restrict__ embp,
                        const float* __restrict__ temb, float* __restrict__ h,
                        _Float16* __restrict__ h16) {
    size_t idx4 = (size_t)blockIdx.x * 256 + threadIdx.x;   // over B*N*H/4
    size_t e0 = idx4 * 4;
    int j = (int)(e0 % H_);
    size_t bn = e0 / H_;
    int n = (int)(bn % N_);
    int b = (int)(bn / N_);
    int a = at[n];
    float4 ep = *(const float4*)(embp + a * H_ + j);
    float4 tv = *(const float4*)(temb + b * H_ + j);
    float4 r = make_float4(ep.x + tv.x, ep.y + tv.y, ep.z + tv.z, ep.w + tv.w);
    ((float4*)h)[idx4] = r;
    f16x4v o;
    o[0] = (_Float16)r.x; o[1] = (_Float16)r.y; o[2] = (_Float16)r.z; o[3] = (_Float16)r.w;
    *(f16x4v*)(h16 + e0) = o;
}

__global__ void k_xcopy(const float* __restrict__ x, float* __restrict__ xb) {
    int i = blockIdx.x * 256 + threadIdx.x;  // 480000 exact
    xb[i] = x[i];
}

// ---------------- MFMA GEMM core (16 rows/wave, wave-local) ----------------
template <int RS, int KT>
__device__ __forceinline__ void mfma_gemm(const _Float16* Asw, const _Float16* __restrict__ Wf,
                                          f32x4 (&acc)[8], int ml, int quad, int lane) {
    #pragma unroll
    for (int kt = 0; kt < KT; ++kt) {
        f16x8 a = *(const f16x8*)(Asw + ml * RS + kt * 32 + quad * 8);
        #pragma unroll
        for (int nt = 0; nt < 8; ++nt) {
            f16x8 b = *(const f16x8*)(Wf + (((kt * 8 + nt) * 64 + lane) * 8));
            acc[nt] = __builtin_amdgcn_mfma_f32_16x16x32_f16(a, b, acc[nt], 0, 0, 0);
        }
    }
}

// ---------------- fp32 tiled GEMM (k_out2 only) ----------------
template <int STRIDE, int K>
__device__ __forceinline__ void gemm_t(const float* As, const float* __restrict__ W,
                                       float (&acc)[4][8], int r4, int c) {
    const float4* Wv = (const float4*)W;
    #pragma unroll 2
    for (int k = 0; k < K; k += 4) {
        float a[4][4];
        #pragma unroll
        for (int i = 0; i < 4; ++i)
            *(float4*)a[i] = *(const float4*)(As + (r4 + i) * STRIDE + k);
        #pragma unroll
        for (int kk = 0; kk < 4; ++kk) {
            float4 w0 = Wv[(k + kk) * 32 + c * 2];
            float4 w1 = Wv[(k + kk) * 32 + c * 2 + 1];
            #pragma unroll
            for (int i = 0; i < 4; ++i) {
                float av = a[i][kk];
                acc[i][0] += av * w0.x; acc[i][1] += av * w0.y;
                acc[i][2] += av * w0.z; acc[i][3] += av * w0.w;
                acc[i][4] += av * w1.x; acc[i][5] += av * w1.y;
                acc[i][6] += av * w1.z; acc[i][7] += av * w1.w;
            }
        }
    }
}

__device__ __forceinline__ void bias_init(float (&acc)[4][8], const float* __restrict__ bias, int c) {
    float4 b0 = ((const float4*)bias)[c * 2];
    float4 b1 = ((const float4*)bias)[c * 2 + 1];
    #pragma unroll
    for (int i = 0; i < 4; ++i) {
        acc[i][0] = b0.x; acc[i][1] = b0.y; acc[i][2] = b0.z; acc[i][3] = b0.w;
        acc[i][4] = b1.x; acc[i][5] = b1.y; acc[i][6] = b1.z; acc[i][7] = b1.w;
    }
}

// ---------------- per-layer kernels ----------------

// 64 edges/block, 4 waves x 16 rows, fully wave-local (NO __syncthreads).
// Split-K GEMM1: stage h_src -> GEMM1a, restage h_dst (same LDS) -> GEMM1b.
// LDS = 64*136*2 + 256 = 17.7 KB -> 6 blocks/CU with launch_bounds(256,6).
// Batch-per-XCD swizzle: b = blockIdx.x & 7 (E_/EPB = 625 chunks exactly).
__global__ __launch_bounds__(256, 6) void k_edge_mfma(
    const _Float16* __restrict__ h16, const float* __restrict__ xcur,
    const int* __restrict__ bond,
    const float* __restrict__ Wm1, const float* __restrict__ bm1,
    const _Float16* __restrict__ Wm1f,
    const float* __restrict__ bm2, const _Float16* __restrict__ Wm2f,
    const float* __restrict__ bc1, const _Float16* __restrict__ Wc1f,
    const float* __restrict__ Wc2,
    _Float16* __restrict__ m16, float* __restrict__ cw_out) {
    __shared__ _Float16 As[EPB * MRS];   // 17408 B
    __shared__ float ds_s[EPB];
    int tid = threadIdx.x;
    int b = blockIdx.x & 7;              // batch -> XCD locality
    int e0 = (blockIdx.x >> 3) * EPB;    // chunk within batch (0..624)
    size_t be0 = (size_t)b * E_ + e0;

    int el = tid >> 2, q = tid & 3;      // 4 threads/row; rows are wave-own
    int2 sd = ((const int2*)bond)[e0 + el];
    int s = sd.x, d = sd.y;
    if (q == 0) {
        const float* xs = xcur + ((size_t)b * N_ + s) * 3;
        const float* xd = xcur + ((size_t)b * N_ + d) * 3;
        float dx = xd[0] - xs[0], dy = xd[1] - xs[1], dz = xd[2] - xs[2];
        ds_s[el] = sqrtf(dx * dx + dy * dy + dz * dz);
    }
    // stage h_src (cols q*32 .. q*32+31)
    {
        const _Float16* hs = h16 + ((size_t)b * N_ + s) * H_;
        #pragma unroll
        for (int j = 0; j < 4; ++j)
            *(f16x8*)(As + el * MRS + q * 32 + j * 8) = *(const f16x8*)(hs + q * 32 + j * 8);
    }
    WFENCE;

    int lane = tid & 63, w = tid >> 6;
    int ml = lane & 15, quad = lane >> 4;
    _Float16* Asw = As + w * 16 * MRS;
    const float* wd = Wm1 + 256 * H_;

    f32x4 acc[8];
    // acc = bm1 + dist*wd
    #pragma unroll
    for (int nt = 0; nt < 8; ++nt) {
        int col = nt * 16 + ml;
        float bb = bm1[col];
        float ww = wd[col];
        #pragma unroll
        for (int r = 0; r < 4; ++r)
            acc[nt][r] = bb + ds_s[w * 16 + quad * 4 + r] * ww;
    }
    mfma_gemm<MRS, 4>(Asw, Wm1f, acc, ml, quad, lane);              // + h_s @ Wm1[0:128]
    WFENCE;
    // restage h_dst over the same LDS (wave-own rows; in-order DS pipe)
    {
        const _Float16* hd = h16 + ((size_t)b * N_ + d) * H_;
        #pragma unroll
        for (int j = 0; j < 4; ++j)
            *(f16x8*)(As + el * MRS + q * 32 + j * 8) = *(const f16x8*)(hd + q * 32 + j * 8);
    }
    WFENCE;
    mfma_gemm<MRS, 4>(Asw, Wm1f + 4 * 8 * 64 * 8, acc, ml, quad, lane);  // + h_d @ Wm1[128:256]
    WFENCE;
    // repack m1 = silu(acc) -> As (wave-own rows)
    #pragma unroll
    for (int nt = 0; nt < 8; ++nt)
        #pragma unroll
        for (int r = 0; r < 4; ++r)
            Asw[(quad * 4 + r) * MRS + nt * 16 + ml] = (_Float16)silu_f(acc[nt][r]);
    WFENCE;

    // ---- GEMM2: m = silu(m1 @ Wm2 + bm2)
    #pragma unroll
    for (int nt = 0; nt < 8; ++nt) {
        float bb = bm2[nt * 16 + ml];
        #pragma unroll
        for (int r = 0; r < 4; ++r) acc[nt][r] = bb;
    }
    mfma_gemm<MRS, 4>(Asw, Wm2f, acc, ml, quad, lane);
    WFENCE;
    // repack m -> As (overwrites m1; this wave's GEMM2 reads are done)
    #pragma unroll
    for (int nt = 0; nt < 8; ++nt)
        #pragma unroll
        for (int r = 0; r < 4; ++r)
            Asw[(quad * 4 + r) * MRS + nt * 16 + ml] = (_Float16)silu_f(acc[nt][r]);
    WFENCE;
    // vectorized coalesced m16 store from LDS (wave-own rows)
    #pragma unroll
    for (int j = 0; j < 4; ++j)
        *(f16x8*)(m16 + (be0 + el) * H_ + q * 32 + j * 8) =
            *(const f16x8*)(As + el * MRS + q * 32 + j * 8);

    // ---- GEMM3: cw = silu(m @ Wc1 + bc1) @ Wc2
    #pragma unroll
    for (int nt = 0; nt < 8; ++nt) {
        float bb = bc1[nt * 16 + ml];
        #pragma unroll
        for (int r = 0; r < 4; ++r) acc[nt][r] = bb;
    }
    mfma_gemm<MRS, 4>(Asw, Wc1f, acc, ml, quad, lane);
    float part[4] = {0.f, 0.f, 0.f, 0.f};
    #pragma unroll
    for (int nt = 0; nt < 8; ++nt) {
        float wv = Wc2[nt * 16 + ml];
        #pragma unroll
        for (int r = 0; r < 4; ++r) part[r] += silu_f(acc[nt][r]) * wv;
    }
    #pragma unroll
    for (int off = 1; off < 16; off <<= 1)
        #pragma unroll
        for (int r = 0; r < 4; ++r) part[r] += __shfl_xor(part[r], off, 64);
    if (ml == 0) {
        #pragma unroll
        for (int r = 0; r < 4; ++r)
            cw_out[be0 + w * 16 + quad * 4 + r] = part[r];
    }
}

__global__ void k_coord(const float* __restrict__ xcur, float* __restrict__ xnext,
                        const float* __restrict__ cw, const int* __restrict__ bond,
                        const int* __restrict__ indptr, const int* __restrict__ adj) {
    int idx = blockIdx.x * 256 + threadIdx.x;   // B*N exact
    int b = idx / N_;
    int n = idx - b * N_;
    const float* xb = xcur + (size_t)b * N_ * 3;
    int p0 = indptr[n], p1 = indptr[n + 1];
    float ax = 0.f, ay = 0.f, az = 0.f;
    for (int p = p0; p < p1; ++p) {
        int a = adj[p];
        int e = a >> 1;
        float sgn = (a & 1) ? 1.f : -1.f;
        int s = bond[2 * e], d = bond[2 * e + 1];
        float dx = xb[d * 3 + 0] - xb[s * 3 + 0];
        float dy = xb[d * 3 + 1] - xb[s * 3 + 1];
        float dz = xb[d * 3 + 2] - xb[s * 3 + 2];
        float dist = sqrtf(dx * dx + dy * dy + dz * dz);
        float w = cw[(size_t)b * E_ + e] * sgn / (dist + 1e-8f);
        ax += dx * w; ay += dy * w; az += dz * w;
    }
    float cnt = (float)max(p1 - p0, 1);
    xnext[(size_t)idx * 3 + 0] = xb[n * 3 + 0] + ax / cnt;
    xnext[(size_t)idx * 3 + 1] = xb[n * 3 + 1] + ay / cnt;
    xnext[(size_t)idx * 3 + 2] = xb[n * 3 + 2] + az / cnt;
}

// 64 nodes/block, wave-local (NO __syncthreads):
// u = silu(h@Wn1a + agg@Wn1b + bn1); h += u@Wn2 + bn2
__global__ __launch_bounds__(256, 5) void k_node_mfma(
    float* __restrict__ h, _Float16* __restrict__ h16,
    const _Float16* __restrict__ m16,
    const int* __restrict__ indptr, const int* __restrict__ adj,
    const float* __restrict__ bn1, const _Float16* __restrict__ Wn1f,
    const float* __restrict__ bn2, const _Float16* __restrict__ Wn2f) {
    __shared__ _Float16 As[NPB * MRS];   // 17408 B
    int tid = threadIdx.x;
    int el = tid >> 2, q = tid & 3;
    int be = blockIdx.x * NPB + el;   // b*N + n
    int b = be / N_, n = be - b * N_;
    // stage h tile (fp16, wave-own rows)
    {
        const _Float16* hr = h16 + (size_t)be * H_;
        #pragma unroll
        for (int j = 0; j < 4; ++j)
            *(f16x8*)(As + el * MRS + q * 32 + j * 8) = *(const f16x8*)(hr + q * 32 + j * 8);
    }
    WFENCE;

    int lane = tid & 63, w = tid >> 6;
    int ml = lane & 15, quad = lane >> 4;
    _Float16* Asw = As + w * 16 * MRS;
    size_t be0 = (size_t)blockIdx.x * NPB;

    f32x4 acc[8];
    #pragma unroll
    for (int nt = 0; nt < 8; ++nt) {
        float bb = bn1[nt * 16 + ml];
        #pragma unroll
        for (int r = 0; r < 4; ++r) acc[nt][r] = bb;
    }
    mfma_gemm<MRS, 4>(Asw, Wn1f, acc, ml, quad, lane);     // + h @ Wn1a
    WFENCE;
    // agg gather -> As (overwrites h tile; wave-own rows; 4 threads/row)
    {
        float ag[4][8];
        #pragma unroll
        for (int j = 0; j < 4; ++j)
            #pragma unroll
            for (int i = 0; i < 8; ++i) ag[j][i] = 0.f;
        int p0 = indptr[n], p1 = indptr[n + 1];
        for (int p = p0; p < p1; ++p) {
            int e = adj[p] >> 1;
            const _Float16* mp = m16 + ((size_t)b * E_ + e) * H_;
            #pragma unroll
            for (int j = 0; j < 4; ++j) {
                f16x8 v = *(const f16x8*)(mp + q * 32 + j * 8);
                #pragma unroll
                for (int i = 0; i < 8; ++i) ag[j][i] += (float)v[i];
            }
        }
        #pragma unroll
        for (int j = 0; j < 4; ++j) {
            f16x8 o;
            #pragma unroll
            for (int i = 0; i < 8; ++i) o[i] = (_Float16)ag[j][i];
            *(f16x8*)(As + el * MRS + q * 32 + j * 8) = o;
        }
    }
    WFENCE;
    mfma_gemm<MRS, 4>(Asw, Wn1f + 4 * 8 * 64 * 8, acc, ml, quad, lane);  // + agg @ Wn1b
    WFENCE;
    // u -> As (wave-own rows)
    #pragma unroll
    for (int nt = 0; nt < 8; ++nt)
        #pragma unroll
        for (int r = 0; r < 4; ++r)
            Asw[(quad * 4 + r) * MRS + nt * 16 + ml] = (_Float16)silu_f(acc[nt][r]);
    WFENCE;
    f32x4 acc2[8];
    #pragma unroll
    for (int nt = 0; nt < 8; ++nt) {
        float bb = bn2[nt * 16 + ml];
        #pragma unroll
        for (int r = 0; r < 4; ++r) acc2[nt][r] = bb;
    }
    mfma_gemm<MRS, 4>(Asw, Wn2f, acc2, ml, quad, lane);
    // residual (fp32 h) + writeback h and h16
    #pragma unroll
    for (int nt = 0; nt < 8; ++nt)
        #pragma unroll
        for (int r = 0; r < 4; ++r) {
            int row = w * 16 + quad * 4 + r;
            size_t g = (size_t)(be0 + row) * H_ + nt * 16 + ml;
            float v = h[g] + acc2[nt][r];
            h[g] = v;
            h16[g] = (_Float16)v;
        }
}

// out = silu(h@Wo1+bo1)@Wo2 + bo2 + (xfin - xorig)  (cross-wave reduce: keep barriers)
__global__ __launch_bounds__(256) void k_out2(
    const float* __restrict__ h, const float* __restrict__ xfin, const float* __restrict__ xorig,
    const float* __restrict__ Wo1, const float* __restrict__ bo1,
    const float* __restrict__ Wo2, const float* __restrict__ bo2,
    float* __restrict__ out) {
    __shared__ float As[64 * TS];
    __shared__ float red[64 * 48];
    int tid = threadIdx.x;
    {
        int nl = tid >> 2, q = tid & 3;
        size_t row = (size_t)blockIdx.x * 64 + nl;
        const float4* hr = (const float4*)(h + row * H_);
        #pragma unroll
        for (int j = 0; j < 8; ++j) {
            int f4 = j * 4 + q;
            *(float4*)(As + nl * TS + f4 * 4) = hr[f4];
        }
    }
    __syncthreads();
    int r4 = (tid >> 4) * 4, c = tid & 15;
    float acc[4][8];
    bias_init(acc, bo1, c);
    gemm_t<TS, 128>(As, Wo1, acc, r4, c);
    #pragma unroll
    for (int i = 0; i < 4; ++i) {
        float p0 = 0.f, p1 = 0.f, p2 = 0.f;
        #pragma unroll
        for (int j = 0; j < 8; ++j) {
            float u = silu_f(acc[i][j]);
            int col = c * 8 + j;
            p0 += u * Wo2[col * 3 + 0];
            p1 += u * Wo2[col * 3 + 1];
            p2 += u * Wo2[col * 3 + 2];
        }
        red[(r4 + i) * 48 + c * 3 + 0] = p0;
        red[(r4 + i) * 48 + c * 3 + 1] = p1;
        red[(r4 + i) * 48 + c * 3 + 2] = p2;
    }
    __syncthreads();
    if (tid < 192) {
        int row = tid / 3, jj = tid - row * 3;
        float s = 0.f;
        #pragma unroll
        for (int cc = 0; cc < 16; ++cc) s += red[row * 48 + cc * 3 + jj];
        size_t grow = (size_t)blockIdx.x * 64 + row;
        out[grow * 3 + jj] = s + bo2[jj] + xfin[grow * 3 + jj] - xorig[grow * 3 + jj];
    }
}

// ---------------- launcher ----------------

extern "C" void kernel_launch(void* const* d_in, const int* in_sizes, int n_in,
                              void* d_out, int out_size, void* d_ws, size_t ws_size,
                              hipStream_t stream) {
    const float* x = (const float*)d_in[0];
    const float* t = (const float*)d_in[1];
    const int* atom_types = (const int*)d_in[2];
    const int* bond = (const int*)d_in[3];
    const float* emb_table = (const float*)d_in[4];
    const float* W_t1 = (const float*)d_in[5];
    const float* b_t1 = (const float*)d_in[6];
    const float* W_t2 = (const float*)d_in[7];
    const float* b_t2 = (const float*)d_in[8];
    const float* W_node = (const float*)d_in[9];
    const float* b_node = (const float*)d_in[10];
    const float* Wm1 = (const float*)d_in[11];
    const float* bm1 = (const float*)d_in[12];
    const float* Wm2 = (const float*)d_in[13];
    const float* bm2 = (const float*)d_in[14];
    const float* Wn1 = (const float*)d_in[15];
    const float* bn1 = (const float*)d_in[16];
    const float* Wn2 = (const float*)d_in[17];
    const float* bn2 = (const float*)d_in[18];
    const float* Wc1 = (const float*)d_in[19];
    const float* bc1 = (const float*)d_in[20];
    const float* Wc2 = (const float*)d_in[21];
    const float* W_o1 = (const float*)d_in[22];
    const float* b_o1 = (const float*)d_in[23];
    const float* W_o2 = (const float*)d_in[24];
    const float* b_o2 = (const float*)d_in[25];
    float* out = (float*)d_out;

    char* p = (char*)d_ws;
    auto alloc = [&](size_t bytes) -> void* {
        void* r = (void*)p;
        p += (bytes + 255) & ~(size_t)255;
        return r;
    };
    // ~211 MB total (R1's 252 MB layout fit; R2's 415 MB overflowed)
    float* t_emb = (float*)alloc((size_t)B_ * H_ * 4);
    float* emb_proj = (float*)alloc((size_t)A_ * H_ * 4);
    int* deg = (int*)alloc((size_t)N_ * 4);
    int* indptr = (int*)alloc((size_t)(N_ + 1) * 4);
    int* cursor = (int*)alloc((size_t)N_ * 4);
    int* adj = (int*)alloc((size_t)2 * E_ * 4);
    float* xb0 = (float*)alloc((size_t)B_ * N_ * 3 * 4);
    float* xb1 = (float*)alloc((size_t)B_ * N_ * 3 * 4);
    float* cw = (float*)alloc((size_t)B_ * E_ * 4);
    float* h = (float*)alloc((size_t)B_ * N_ * H_ * 4);
    _Float16* h16 = (_Float16*)alloc((size_t)B_ * N_ * H_ * 2);
    _Float16* m16 = (_Float16*)alloc((size_t)B_ * E_ * H_ * 2);
    _Float16* Wm1f = (_Float16*)alloc((size_t)L_ * 256 * H_ * 2);
    _Float16* Wm2f = (_Float16*)alloc((size_t)L_ * H_ * H_ * 2);
    _Float16* Wc1f = (_Float16*)alloc((size_t)L_ * H_ * H_ * 2);
    _Float16* Wn1f = (_Float16*)alloc((size_t)L_ * 256 * H_ * 2);
    _Float16* Wn2f = (_Float16*)alloc((size_t)L_ * H_ * H_ * 2);

    k_zero<<<(N_ + 255) / 256, 256, 0, stream>>>(deg, cursor);
    k_deg<<<(E_ + 255) / 256, 256, 0, stream>>>(bond, deg);
    k_scan<<<1, 1024, 0, stream>>>(deg, indptr);
    k_fill<<<(E_ + 255) / 256, 256, 0, stream>>>(bond, indptr, cursor, adj);
    k_temb<<<B_, 128, 0, stream>>>(t, W_t1, b_t1, W_t2, b_t2, t_emb);
    k_embproj<<<1, 512, 0, stream>>>(emb_table, W_node, b_node, emb_proj);
    k_hinit<<<(B_ * N_ * H_ / 4) / 256, 256, 0, stream>>>(atom_types, emb_proj, t_emb, h, h16);
    k_xcopy<<<(B_ * N_ * 3) / 256, 256, 0, stream>>>(x, xb0);
    // weight prep: one launch per weight type, layer via blockIdx.y
    k_wprepL<<<dim3(128, L_), 256, 0, stream>>>(Wm1, Wm1f, 256, 257 * H_);
    k_wprepL<<<dim3(64, L_), 256, 0, stream>>>(Wm2, Wm2f, 128, H_ * H_);
    k_wprepL<<<dim3(64, L_), 256, 0, stream>>>(Wc1, Wc1f, 128, H_ * H_);
    k_wprepL<<<dim3(128, L_), 256, 0, stream>>>(Wn1, Wn1f, 256, 2 * H_ * H_);
    k_wprepL<<<dim3(64, L_), 256, 0, stream>>>(Wn2, Wn2f, 128, H_ * H_);

    float* xc = xb0;
    float* xn = xb1;
    for (int l = 0; l < L_; ++l) {
        k_edge_mfma<<<(B_ * E_) / EPB, 256, 0, stream>>>(
            h16, xc, bond,
            Wm1 + (size_t)l * 257 * H_, bm1 + l * H_, Wm1f + (size_t)l * 256 * H_,
            bm2 + l * H_, Wm2f + (size_t)l * H_ * H_,
            bc1 + l * H_, Wc1f + (size_t)l * H_ * H_,
            Wc2 + (size_t)l * H_, m16, cw);
        k_coord<<<(B_ * N_) / 256, 256, 0, stream>>>(xc, xn, cw, bond, indptr, adj);
        k_node_mfma<<<(B_ * N_) / NPB, 256, 0, stream>>>(
            h, h16, m16, indptr, adj,
            bn1 + l * H_, Wn1f + (size_t)l * 256 * H_,
            bn2 + l * H_, Wn2f + (size_t)l * H_ * H_);
        float* tmp = xc; xc = xn; xn = tmp;
    }
    k_out2<<<(B_ * N_) / 64, 256, 0, stream>>>(h, xc, x, W_o1, b_o1, W_o2, b_o2, out);
}

// Round 8
// 1160.146 us; speedup vs baseline: 1.4314x; 1.0300x over previous
//
#include <hip/hip_runtime.h>
#include <math.h>

#define B_ 8
#define N_ 20000
#define E_ 40000
#define H_ 128
#define L_ 4
#define A_ 4
#define TS 132    // fp32 LDS row stride (k_out2)
#define MRS 136   // fp16 LDS row stride (128+8), edge + node kernels
#define EPB 64    // edges per block
#define NPB 64    // nodes per block

// compiler-only memory fence: orders LDS ops across phases without s_barrier
#define WFENCE __asm__ __volatile__("" ::: "memory")

typedef _Float16 f16x8 __attribute__((ext_vector_type(8)));
typedef _Float16 f16x4v __attribute__((ext_vector_type(4)));
typedef float f32x4 __attribute__((ext_vector_type(4)));

// silu via raw v_rcp_f32 (~1 ulp) — avoids the IEEE fdiv expansion (~11 VALU inst)
__device__ __forceinline__ float silu_f(float x) {
    return x * __builtin_amdgcn_rcpf(1.f + __expf(-x));
}

// ---------------- setup kernels ----------------

__global__ void k_zero(int* __restrict__ deg, int* __restrict__ cursor) {
    int i = blockIdx.x * 256 + threadIdx.x;
    if (i < N_) { deg[i] = 0; cursor[i] = 0; }
}

__global__ void k_deg(const int* __restrict__ bond, int* __restrict__ deg) {
    int e = blockIdx.x * 256 + threadIdx.x;
    if (e < E_) {
        atomicAdd(&deg[bond[2 * e]], 1);
        atomicAdd(&deg[bond[2 * e + 1]], 1);
    }
}

__global__ void k_scan(const int* __restrict__ deg, int* __restrict__ indptr) {
    __shared__ int sums[1024];
    const int CH = (N_ + 1023) / 1024;  // 20
    int t = threadIdx.x;
    int s0 = t * CH;
    int s1 = min(s0 + CH, N_);
    int s = 0;
    for (int i = s0; i < s1; ++i) s += deg[i];
    sums[t] = s;
    __syncthreads();
    for (int off = 1; off < 1024; off <<= 1) {
        int v = (t >= off) ? sums[t - off] : 0;
        __syncthreads();
        sums[t] += v;
        __syncthreads();
    }
    int base = (t > 0) ? sums[t - 1] : 0;
    int run = base;
    for (int i = s0; i < s1; ++i) { indptr[i] = run; run += deg[i]; }
    if (s1 == N_ && s0 < N_) indptr[N_] = run;
}

__global__ void k_fill(const int* __restrict__ bond, const int* __restrict__ indptr,
                       int* __restrict__ cursor, int* __restrict__ adj) {
    int e = blockIdx.x * 256 + threadIdx.x;
    if (e < E_) {
        int s = bond[2 * e], d = bond[2 * e + 1];
        int ps = indptr[s] + atomicAdd(&cursor[s], 1);
        adj[ps] = (e << 1);        // node is src -> sign -
        int pd = indptr[d] + atomicAdd(&cursor[d], 1);
        adj[pd] = (e << 1) | 1;    // node is dst -> sign +
    }
}

// Convert W[K][128] fp32 -> B-fragment-layout fp16 for mfma_f32_16x16x32_f16.
// blockIdx.y = layer; strides passed per weight type.
__global__ void k_wprepL(const float* __restrict__ W, _Float16* __restrict__ Wf,
                         int K, int wstride) {
    int l = blockIdx.y;
    const float* Wl = W + (size_t)l * wstride;
    _Float16* Wfl = Wf + (size_t)l * K * 128;
    int idx = blockIdx.x * 256 + threadIdx.x;
    if (idx >= K * 128) return;
    int j = idx & 7, lane = (idx >> 3) & 63, nt = (idx >> 9) & 7, kt = idx >> 12;
    int k = kt * 32 + (lane >> 4) * 8 + j;
    int n = nt * 16 + (lane & 15);
    Wfl[idx] = (_Float16)Wl[k * 128 + n];
}

__global__ void k_temb(const float* __restrict__ tv,
                       const float* __restrict__ W1, const float* __restrict__ b1,
                       const float* __restrict__ W2, const float* __restrict__ b2,
                       float* __restrict__ t_emb) {
    __shared__ float te[64];
    __shared__ float h1[128];
    int b = blockIdx.x;
    int tid = threadIdx.x;
    float tval = tv[b];
    if (tid < 32) {
        float fr = __expf((float)tid * (-logf(10000.f) / 31.f));
        float a = tval * fr;
        te[tid] = sinf(a);
        te[tid + 32] = cosf(a);
    }
    __syncthreads();
    float acc = b1[tid];
    for (int k = 0; k < 64; ++k) acc += te[k] * W1[k * 128 + tid];
    h1[tid] = silu_f(acc);
    __syncthreads();
    float acc2 = b2[tid];
    for (int k = 0; k < 128; ++k) acc2 += h1[k] * W2[k * 128 + tid];
    t_emb[b * 128 + tid] = acc2;
}

__global__ void k_embproj(const float* __restrict__ emb, const float* __restrict__ W,
                          const float* __restrict__ bias, float* __restrict__ outp) {
    int tid = threadIdx.x;       // 512 threads
    int a = tid >> 7, j = tid & 127;
    float acc = bias[j];
    for (int k = 0; k < 128; ++k) acc += emb[a * 128 + k] * W[k * 128 + j];
    outp[a * 128 + j] = acc;
}

__global__ void k_hinit(const int* __restrict__ at, const float* __restrict__ embp,
                        const float* __restrict__ temb, float* __restrict__ h,
                        _Float16* __restrict__ h16) {
    size_t idx4 = (size_t)blockIdx.x * 256 + threadIdx.x;   // over B*N*H/4
    size_t e0 = idx4 * 4;
    int j = (int)(e0 % H_);
    size_t bn = e0 / H_;
    int n = (int)(bn % N_);
    int b = (int)(bn / N_);
    int a = at[n];
    float4 ep = *(const float4*)(embp + a * H_ + j);
    float4 tv = *(const float4*)(temb + b * H_ + j);
    float4 r = make_float4(ep.x + tv.x, ep.y + tv.y, ep.z + tv.z, ep.w + tv.w);
    ((float4*)h)[idx4] = r;
    f16x4v o;
    o[0] = (_Float16)r.x; o[1] = (_Float16)r.y; o[2] = (_Float16)r.z; o[3] = (_Float16)r.w;
    *(f16x4v*)(h16 + e0) = o;
}

__global__ void k_xcopy(const float* __restrict__ x, float* __restrict__ xb) {
    int i = blockIdx.x * 256 + threadIdx.x;  // 480000 exact
    xb[i] = x[i];
}

// ---------------- MFMA GEMM core (16 rows/wave, wave-local) ----------------
template <int RS, int KT>
__device__ __forceinline__ void mfma_gemm(const _Float16* Asw, const _Float16* __restrict__ Wf,
                                          f32x4 (&acc)[8], int ml, int quad, int lane) {
    #pragma unroll
    for (int kt = 0; kt < KT; ++kt) {
        f16x8 a = *(const f16x8*)(Asw + ml * RS + kt * 32 + quad * 8);
        #pragma unroll
        for (int nt = 0; nt < 8; ++nt) {
            f16x8 b = *(const f16x8*)(Wf + (((kt * 8 + nt) * 64 + lane) * 8));
            acc[nt] = __builtin_amdgcn_mfma_f32_16x16x32_f16(a, b, acc[nt], 0, 0, 0);
        }
    }
}

// ---------------- fp32 tiled GEMM (k_out2 only) ----------------
template <int STRIDE, int K>
__device__ __forceinline__ void gemm_t(const float* As, const float* __restrict__ W,
                                       float (&acc)[4][8], int r4, int c) {
    const float4* Wv = (const float4*)W;
    #pragma unroll 2
    for (int k = 0; k < K; k += 4) {
        float a[4][4];
        #pragma unroll
        for (int i = 0; i < 4; ++i)
            *(float4*)a[i] = *(const float4*)(As + (r4 + i) * STRIDE + k);
        #pragma unroll
        for (int kk = 0; kk < 4; ++kk) {
            float4 w0 = Wv[(k + kk) * 32 + c * 2];
            float4 w1 = Wv[(k + kk) * 32 + c * 2 + 1];
            #pragma unroll
            for (int i = 0; i < 4; ++i) {
                float av = a[i][kk];
                acc[i][0] += av * w0.x; acc[i][1] += av * w0.y;
                acc[i][2] += av * w0.z; acc[i][3] += av * w0.w;
                acc[i][4] += av * w1.x; acc[i][5] += av * w1.y;
                acc[i][6] += av * w1.z; acc[i][7] += av * w1.w;
            }
        }
    }
}

__device__ __forceinline__ void bias_init(float (&acc)[4][8], const float* __restrict__ bias, int c) {
    float4 b0 = ((const float4*)bias)[c * 2];
    float4 b1 = ((const float4*)bias)[c * 2 + 1];
    #pragma unroll
    for (int i = 0; i < 4; ++i) {
        acc[i][0] = b0.x; acc[i][1] = b0.y; acc[i][2] = b0.z; acc[i][3] = b0.w;
        acc[i][4] = b1.x; acc[i][5] = b1.y; acc[i][6] = b1.z; acc[i][7] = b1.w;
    }
}

// ---------------- per-layer kernels ----------------

// 64 edges/block, 4 waves x 16 rows, fully wave-local (NO __syncthreads).
// Split-K GEMM1: stage h_src -> GEMM1a, restage h_dst (same LDS) -> GEMM1b.
// Batch-per-XCD swizzle: b = blockIdx.x & 7 (E_/EPB = 625 chunks exactly).
__global__ __launch_bounds__(256, 6) void k_edge_mfma(
    const _Float16* __restrict__ h16, const float* __restrict__ xcur,
    const int* __restrict__ bond,
    const float* __restrict__ Wm1, const float* __restrict__ bm1,
    const _Float16* __restrict__ Wm1f,
    const float* __restrict__ bm2, const _Float16* __restrict__ Wm2f,
    const float* __restrict__ bc1, const _Float16* __restrict__ Wc1f,
    const float* __restrict__ Wc2,
    _Float16* __restrict__ m16, float* __restrict__ cw_out) {
    __shared__ _Float16 As[EPB * MRS];   // 17408 B
    __shared__ float ds_s[EPB];
    int tid = threadIdx.x;
    int b = blockIdx.x & 7;              // batch -> XCD locality
    int e0 = (blockIdx.x >> 3) * EPB;    // chunk within batch (0..624)
    size_t be0 = (size_t)b * E_ + e0;

    int el = tid >> 2, q = tid & 3;      // 4 threads/row; rows are wave-own
    int2 sd = ((const int2*)bond)[e0 + el];
    int s = sd.x, d = sd.y;
    if (q == 0) {
        const float* xs = xcur + ((size_t)b * N_ + s) * 3;
        const float* xd = xcur + ((size_t)b * N_ + d) * 3;
        float dx = xd[0] - xs[0], dy = xd[1] - xs[1], dz = xd[2] - xs[2];
        ds_s[el] = sqrtf(dx * dx + dy * dy + dz * dz);
    }
    // stage h_src (cols q*32 .. q*32+31)
    {
        const _Float16* hs = h16 + ((size_t)b * N_ + s) * H_;
        #pragma unroll
        for (int j = 0; j < 4; ++j)
            *(f16x8*)(As + el * MRS + q * 32 + j * 8) = *(const f16x8*)(hs + q * 32 + j * 8);
    }
    WFENCE;

    int lane = tid & 63, w = tid >> 6;
    int ml = lane & 15, quad = lane >> 4;
    _Float16* Asw = As + w * 16 * MRS;
    const float* wd = Wm1 + 256 * H_;

    f32x4 acc[8];
    // acc = bm1 + dist*wd
    #pragma unroll
    for (int nt = 0; nt < 8; ++nt) {
        int col = nt * 16 + ml;
        float bb = bm1[col];
        float ww = wd[col];
        #pragma unroll
        for (int r = 0; r < 4; ++r)
            acc[nt][r] = bb + ds_s[w * 16 + quad * 4 + r] * ww;
    }
    mfma_gemm<MRS, 4>(Asw, Wm1f, acc, ml, quad, lane);              // + h_s @ Wm1[0:128]
    WFENCE;
    // restage h_dst over the same LDS (wave-own rows; in-order DS pipe)
    {
        const _Float16* hd = h16 + ((size_t)b * N_ + d) * H_;
        #pragma unroll
        for (int j = 0; j < 4; ++j)
            *(f16x8*)(As + el * MRS + q * 32 + j * 8) = *(const f16x8*)(hd + q * 32 + j * 8);
    }
    WFENCE;
    mfma_gemm<MRS, 4>(Asw, Wm1f + 4 * 8 * 64 * 8, acc, ml, quad, lane);  // + h_d @ Wm1[128:256]
    WFENCE;
    // repack m1 = silu(acc) -> As (wave-own rows)
    #pragma unroll
    for (int nt = 0; nt < 8; ++nt)
        #pragma unroll
        for (int r = 0; r < 4; ++r)
            Asw[(quad * 4 + r) * MRS + nt * 16 + ml] = (_Float16)silu_f(acc[nt][r]);
    WFENCE;

    // ---- GEMM2: m = silu(m1 @ Wm2 + bm2)
    #pragma unroll
    for (int nt = 0; nt < 8; ++nt) {
        float bb = bm2[nt * 16 + ml];
        #pragma unroll
        for (int r = 0; r < 4; ++r) acc[nt][r] = bb;
    }
    mfma_gemm<MRS, 4>(Asw, Wm2f, acc, ml, quad, lane);
    WFENCE;
    // repack m -> As (overwrites m1; this wave's GEMM2 reads are done)
    #pragma unroll
    for (int nt = 0; nt < 8; ++nt)
        #pragma unroll
        for (int r = 0; r < 4; ++r)
            Asw[(quad * 4 + r) * MRS + nt * 16 + ml] = (_Float16)silu_f(acc[nt][r]);
    WFENCE;
    // vectorized coalesced m16 store from LDS (wave-own rows)
    #pragma unroll
    for (int j = 0; j < 4; ++j)
        *(f16x8*)(m16 + (be0 + el) * H_ + q * 32 + j * 8) =
            *(const f16x8*)(As + el * MRS + q * 32 + j * 8);

    // ---- GEMM3: cw = silu(m @ Wc1 + bc1) @ Wc2
    #pragma unroll
    for (int nt = 0; nt < 8; ++nt) {
        float bb = bc1[nt * 16 + ml];
        #pragma unroll
        for (int r = 0; r < 4; ++r) acc[nt][r] = bb;
    }
    mfma_gemm<MRS, 4>(Asw, Wc1f, acc, ml, quad, lane);
    float part[4] = {0.f, 0.f, 0.f, 0.f};
    #pragma unroll
    for (int nt = 0; nt < 8; ++nt) {
        float wv = Wc2[nt * 16 + ml];
        #pragma unroll
        for (int r = 0; r < 4; ++r) part[r] += silu_f(acc[nt][r]) * wv;
    }
    #pragma unroll
    for (int off = 1; off < 16; off <<= 1)
        #pragma unroll
        for (int r = 0; r < 4; ++r) part[r] += __shfl_xor(part[r], off, 64);
    if (ml == 0) {
        #pragma unroll
        for (int r = 0; r < 4; ++r)
            cw_out[be0 + w * 16 + quad * 4 + r] = part[r];
    }
}

__global__ void k_coord(const float* __restrict__ xcur, float* __restrict__ xnext,
                        const float* __restrict__ cw, const int* __restrict__ bond,
                        const int* __restrict__ indptr, const int* __restrict__ adj) {
    int idx = blockIdx.x * 256 + threadIdx.x;   // B*N exact
    int b = idx / N_;
    int n = idx - b * N_;
    const float* xb = xcur + (size_t)b * N_ * 3;
    int p0 = indptr[n], p1 = indptr[n + 1];
    float ax = 0.f, ay = 0.f, az = 0.f;
    for (int p = p0; p < p1; ++p) {
        int a = adj[p];
        int e = a >> 1;
        float sgn = (a & 1) ? 1.f : -1.f;
        int s = bond[2 * e], d = bond[2 * e + 1];
        float dx = xb[d * 3 + 0] - xb[s * 3 + 0];
        float dy = xb[d * 3 + 1] - xb[s * 3 + 1];
        float dz = xb[d * 3 + 2] - xb[s * 3 + 2];
        float dist = sqrtf(dx * dx + dy * dy + dz * dz);
        float w = cw[(size_t)b * E_ + e] * sgn * __builtin_amdgcn_rcpf(dist + 1e-8f);
        ax += dx * w; ay += dy * w; az += dz * w;
    }
    float rcnt = __builtin_amdgcn_rcpf((float)max(p1 - p0, 1));
    xnext[(size_t)idx * 3 + 0] = xb[n * 3 + 0] + ax * rcnt;
    xnext[(size_t)idx * 3 + 1] = xb[n * 3 + 1] + ay * rcnt;
    xnext[(size_t)idx * 3 + 2] = xb[n * 3 + 2] + az * rcnt;
}

// 64 nodes/block, wave-local (NO __syncthreads):
// u = silu(h@Wn1a + agg@Wn1b + bn1); h += u@Wn2 + bn2
__global__ __launch_bounds__(256, 5) void k_node_mfma(
    float* __restrict__ h, _Float16* __restrict__ h16,
    const _Float16* __restrict__ m16,
    const int* __restrict__ indptr, const int* __restrict__ adj,
    const float* __restrict__ bn1, const _Float16* __restrict__ Wn1f,
    const float* __restrict__ bn2, const _Float16* __restrict__ Wn2f) {
    __shared__ _Float16 As[NPB * MRS];   // 17408 B
    int tid = threadIdx.x;
    int el = tid >> 2, q = tid & 3;
    int be = blockIdx.x * NPB + el;   // b*N + n
    int b = be / N_, n = be - b * N_;
    // stage h tile (fp16, wave-own rows)
    {
        const _Float16* hr = h16 + (size_t)be * H_;
        #pragma unroll
        for (int j = 0; j < 4; ++j)
            *(f16x8*)(As + el * MRS + q * 32 + j * 8) = *(const f16x8*)(hr + q * 32 + j * 8);
    }
    WFENCE;

    int lane = tid & 63, w = tid >> 6;
    int ml = lane & 15, quad = lane >> 4;
    _Float16* Asw = As + w * 16 * MRS;
    size_t be0 = (size_t)blockIdx.x * NPB;

    f32x4 acc[8];
    #pragma unroll
    for (int nt = 0; nt < 8; ++nt) {
        float bb = bn1[nt * 16 + ml];
        #pragma unroll
        for (int r = 0; r < 4; ++r) acc[nt][r] = bb;
    }
    mfma_gemm<MRS, 4>(Asw, Wn1f, acc, ml, quad, lane);     // + h @ Wn1a
    WFENCE;
    // agg gather -> As (overwrites h tile; wave-own rows; 4 threads/row)
    {
        float ag[4][8];
        #pragma unroll
        for (int j = 0; j < 4; ++j)
            #pragma unroll
            for (int i = 0; i < 8; ++i) ag[j][i] = 0.f;
        int p0 = indptr[n], p1 = indptr[n + 1];
        for (int p = p0; p < p1; ++p) {
            int e = adj[p] >> 1;
            const _Float16* mp = m16 + ((size_t)b * E_ + e) * H_;
            #pragma unroll
            for (int j = 0; j < 4; ++j) {
                f16x8 v = *(const f16x8*)(mp + q * 32 + j * 8);
                #pragma unroll
                for (int i = 0; i < 8; ++i) ag[j][i] += (float)v[i];
            }
        }
        #pragma unroll
        for (int j = 0; j < 4; ++j) {
            f16x8 o;
            #pragma unroll
            for (int i = 0; i < 8; ++i) o[i] = (_Float16)ag[j][i];
            *(f16x8*)(As + el * MRS + q * 32 + j * 8) = o;
        }
    }
    WFENCE;
    mfma_gemm<MRS, 4>(Asw, Wn1f + 4 * 8 * 64 * 8, acc, ml, quad, lane);  // + agg @ Wn1b
    WFENCE;
    // u -> As (wave-own rows)
    #pragma unroll
    for (int nt = 0; nt < 8; ++nt)
        #pragma unroll
        for (int r = 0; r < 4; ++r)
            Asw[(quad * 4 + r) * MRS + nt * 16 + ml] = (_Float16)silu_f(acc[nt][r]);
    WFENCE;
    f32x4 acc2[8];
    #pragma unroll
    for (int nt = 0; nt < 8; ++nt) {
        float bb = bn2[nt * 16 + ml];
        #pragma unroll
        for (int r = 0; r < 4; ++r) acc2[nt][r] = bb;
    }
    mfma_gemm<MRS, 4>(Asw, Wn2f, acc2, ml, quad, lane);
    // residual (fp32 h) + writeback h and h16
    #pragma unroll
    for (int nt = 0; nt < 8; ++nt)
        #pragma unroll
        for (int r = 0; r < 4; ++r) {
            int row = w * 16 + quad * 4 + r;
            size_t g = (size_t)(be0 + row) * H_ + nt * 16 + ml;
            float v = h[g] + acc2[nt][r];
            h[g] = v;
            h16[g] = (_Float16)v;
        }
}

// out = silu(h@Wo1+bo1)@Wo2 + bo2 + (xfin - xorig)  (cross-wave reduce: keep barriers)
__global__ __launch_bounds__(256) void k_out2(
    const float* __restrict__ h, const float* __restrict__ xfin, const float* __restrict__ xorig,
    const float* __restrict__ Wo1, const float* __restrict__ bo1,
    const float* __restrict__ Wo2, const float* __restrict__ bo2,
    float* __restrict__ out) {
    __shared__ float As[64 * TS];
    __shared__ float red[64 * 48];
    int tid = threadIdx.x;
    {
        int nl = tid >> 2, q = tid & 3;
        size_t row = (size_t)blockIdx.x * 64 + nl;
        const float4* hr = (const float4*)(h + row * H_);
        #pragma unroll
        for (int j = 0; j < 8; ++j) {
            int f4 = j * 4 + q;
            *(float4*)(As + nl * TS + f4 * 4) = hr[f4];
        }
    }
    __syncthreads();
    int r4 = (tid >> 4) * 4, c = tid & 15;
    float acc[4][8];
    bias_init(acc, bo1, c);
    gemm_t<TS, 128>(As, Wo1, acc, r4, c);
    #pragma unroll
    for (int i = 0; i < 4; ++i) {
        float p0 = 0.f, p1 = 0.f, p2 = 0.f;
        #pragma unroll
        for (int j = 0; j < 8; ++j) {
            float u = silu_f(acc[i][j]);
            int col = c * 8 + j;
            p0 += u * Wo2[col * 3 + 0];
            p1 += u * Wo2[col * 3 + 1];
            p2 += u * Wo2[col * 3 + 2];
        }
        red[(r4 + i) * 48 + c * 3 + 0] = p0;
        red[(r4 + i) * 48 + c * 3 + 1] = p1;
        red[(r4 + i) * 48 + c * 3 + 2] = p2;
    }
    __syncthreads();
    if (tid < 192) {
        int row = tid / 3, jj = tid - row * 3;
        float s = 0.f;
        #pragma unroll
        for (int cc = 0; cc < 16; ++cc) s += red[row * 48 + cc * 3 + jj];
        size_t grow = (size_t)blockIdx.x * 64 + row;
        out[grow * 3 + jj] = s + bo2[jj] + xfin[grow * 3 + jj] - xorig[grow * 3 + jj];
    }
}

// ---------------- launcher ----------------

extern "C" void kernel_launch(void* const* d_in, const int* in_sizes, int n_in,
                              void* d_out, int out_size, void* d_ws, size_t ws_size,
                              hipStream_t stream) {
    const float* x = (const float*)d_in[0];
    const float* t = (const float*)d_in[1];
    const int* atom_types = (const int*)d_in[2];
    const int* bond = (const int*)d_in[3];
    const float* emb_table = (const float*)d_in[4];
    const float* W_t1 = (const float*)d_in[5];
    const float* b_t1 = (const float*)d_in[6];
    const float* W_t2 = (const float*)d_in[7];
    const float* b_t2 = (const float*)d_in[8];
    const float* W_node = (const float*)d_in[9];
    const float* b_node = (const float*)d_in[10];
    const float* Wm1 = (const float*)d_in[11];
    const float* bm1 = (const float*)d_in[12];
    const float* Wm2 = (const float*)d_in[13];
    const float* bm2 = (const float*)d_in[14];
    const float* Wn1 = (const float*)d_in[15];
    const float* bn1 = (const float*)d_in[16];
    const float* Wn2 = (const float*)d_in[17];
    const float* bn2 = (const float*)d_in[18];
    const float* Wc1 = (const float*)d_in[19];
    const float* bc1 = (const float*)d_in[20];
    const float* Wc2 = (const float*)d_in[21];
    const float* W_o1 = (const float*)d_in[22];
    const float* b_o1 = (const float*)d_in[23];
    const float* W_o2 = (const float*)d_in[24];
    const float* b_o2 = (const float*)d_in[25];
    float* out = (float*)d_out;

    char* p = (char*)d_ws;
    auto alloc = [&](size_t bytes) -> void* {
        void* r = (void*)p;
        p += (bytes + 255) & ~(size_t)255;
        return r;
    };
    // ~211 MB total (R1's 252 MB layout fit; R2's 415 MB overflowed)
    float* t_emb = (float*)alloc((size_t)B_ * H_ * 4);
    float* emb_proj = (float*)alloc((size_t)A_ * H_ * 4);
    int* deg = (int*)alloc((size_t)N_ * 4);
    int* indptr = (int*)alloc((size_t)(N_ + 1) * 4);
    int* cursor = (int*)alloc((size_t)N_ * 4);
    int* adj = (int*)alloc((size_t)2 * E_ * 4);
    float* xb0 = (float*)alloc((size_t)B_ * N_ * 3 * 4);
    float* xb1 = (float*)alloc((size_t)B_ * N_ * 3 * 4);
    float* cw = (float*)alloc((size_t)B_ * E_ * 4);
    float* h = (float*)alloc((size_t)B_ * N_ * H_ * 4);
    _Float16* h16 = (_Float16*)alloc((size_t)B_ * N_ * H_ * 2);
    _Float16* m16 = (_Float16*)alloc((size_t)B_ * E_ * H_ * 2);
    _Float16* Wm1f = (_Float16*)alloc((size_t)L_ * 256 * H_ * 2);
    _Float16* Wm2f = (_Float16*)alloc((size_t)L_ * H_ * H_ * 2);
    _Float16* Wc1f = (_Float16*)alloc((size_t)L_ * H_ * H_ * 2);
    _Float16* Wn1f = (_Float16*)alloc((size_t)L_ * 256 * H_ * 2);
    _Float16* Wn2f = (_Float16*)alloc((size_t)L_ * H_ * H_ * 2);

    k_zero<<<(N_ + 255) / 256, 256, 0, stream>>>(deg, cursor);
    k_deg<<<(E_ + 255) / 256, 256, 0, stream>>>(bond, deg);
    k_scan<<<1, 1024, 0, stream>>>(deg, indptr);
    k_fill<<<(E_ + 255) / 256, 256, 0, stream>>>(bond, indptr, cursor, adj);
    k_temb<<<B_, 128, 0, stream>>>(t, W_t1, b_t1, W_t2, b_t2, t_emb);
    k_embproj<<<1, 512, 0, stream>>>(emb_table, W_node, b_node, emb_proj);
    k_hinit<<<(B_ * N_ * H_ / 4) / 256, 256, 0, stream>>>(atom_types, emb_proj, t_emb, h, h16);
    k_xcopy<<<(B_ * N_ * 3) / 256, 256, 0, stream>>>(x, xb0);
    // weight prep: one launch per weight type, layer via blockIdx.y
    k_wprepL<<<dim3(128, L_), 256, 0, stream>>>(Wm1, Wm1f, 256, 257 * H_);
    k_wprepL<<<dim3(64, L_), 256, 0, stream>>>(Wm2, Wm2f, 128, H_ * H_);
    k_wprepL<<<dim3(64, L_), 256, 0, stream>>>(Wc1, Wc1f, 128, H_ * H_);
    k_wprepL<<<dim3(128, L_), 256, 0, stream>>>(Wn1, Wn1f, 256, 2 * H_ * H_);
    k_wprepL<<<dim3(64, L_), 256, 0, stream>>>(Wn2, Wn2f, 128, H_ * H_);

    float* xc = xb0;
    float* xn = xb1;
    for (int l = 0; l < L_; ++l) {
        k_edge_mfma<<<(B_ * E_) / EPB, 256, 0, stream>>>(
            h16, xc, bond,
            Wm1 + (size_t)l * 257 * H_, bm1 + l * H_, Wm1f + (size_t)l * 256 * H_,
            bm2 + l * H_, Wm2f + (size_t)l * H_ * H_,
            bc1 + l * H_, Wc1f + (size_t)l * H_ * H_,
            Wc2 + (size_t)l * H_, m16, cw);
        k_coord<<<(B_ * N_) / 256, 256, 0, stream>>>(xc, xn, cw, bond, indptr, adj);
        k_node_mfma<<<(B_ * N_) / NPB, 256, 0, stream>>>(
            h, h16, m16, indptr, adj,
            bn1 + l * H_, Wn1f + (size_t)l * 256 * H_,
            bn2 + l * H_, Wn2f + (size_t)l * H_ * H_);
        float* tmp = xc; xc = xn; xn = tmp;
    }
    k_out2<<<(B_ * N_) / 64, 256, 0, stream>>>(h, xc, x, W_o1, b_o1, W_o2, b_o2, out);
}

// Round 9
// 1132.224 us; speedup vs baseline: 1.4667x; 1.0247x over previous
//
#include <hip/hip_runtime.h>
#include <math.h>

#define B_ 8
#define N_ 20000
#define E_ 40000
#define H_ 128
#define L_ 4
#define A_ 4
#define TS 132    // fp32 LDS row stride (k_out2)
#define MRS 136   // fp16 LDS row stride (128+8), edge + node kernels
#define EPB 64    // edges per block
#define NPB 64    // nodes per block

// compiler-only memory fence: orders LDS ops across phases without s_barrier
#define WFENCE __asm__ __volatile__("" ::: "memory")

typedef _Float16 f16x8 __attribute__((ext_vector_type(8)));
typedef _Float16 f16x4v __attribute__((ext_vector_type(4)));
typedef float f32x4 __attribute__((ext_vector_type(4)));

// silu via raw v_rcp_f32 (~1 ulp) — avoids the IEEE fdiv expansion (~11 VALU inst)
__device__ __forceinline__ float silu_f(float x) {
    return x * __builtin_amdgcn_rcpf(1.f + __expf(-x));
}

// ---------------- setup kernels ----------------

__global__ void k_zero(int* __restrict__ deg, int* __restrict__ cursor) {
    int i = blockIdx.x * 256 + threadIdx.x;
    if (i < N_) { deg[i] = 0; cursor[i] = 0; }
}

__global__ void k_deg(const int* __restrict__ bond, int* __restrict__ deg) {
    int e = blockIdx.x * 256 + threadIdx.x;
    if (e < E_) {
        atomicAdd(&deg[bond[2 * e]], 1);
        atomicAdd(&deg[bond[2 * e + 1]], 1);
    }
}

__global__ void k_scan(const int* __restrict__ deg, int* __restrict__ indptr) {
    __shared__ int sums[1024];
    const int CH = (N_ + 1023) / 1024;  // 20
    int t = threadIdx.x;
    int s0 = t * CH;
    int s1 = min(s0 + CH, N_);
    int s = 0;
    for (int i = s0; i < s1; ++i) s += deg[i];
    sums[t] = s;
    __syncthreads();
    for (int off = 1; off < 1024; off <<= 1) {
        int v = (t >= off) ? sums[t - off] : 0;
        __syncthreads();
        sums[t] += v;
        __syncthreads();
    }
    int base = (t > 0) ? sums[t - 1] : 0;
    int run = base;
    for (int i = s0; i < s1; ++i) { indptr[i] = run; run += deg[i]; }
    if (s1 == N_ && s0 < N_) indptr[N_] = run;
}

__global__ void k_fill(const int* __restrict__ bond, const int* __restrict__ indptr,
                       int* __restrict__ cursor, int* __restrict__ adj) {
    int e = blockIdx.x * 256 + threadIdx.x;
    if (e < E_) {
        int s = bond[2 * e], d = bond[2 * e + 1];
        int ps = indptr[s] + atomicAdd(&cursor[s], 1);
        adj[ps] = (e << 1);        // node is src -> sign -
        int pd = indptr[d] + atomicAdd(&cursor[d], 1);
        adj[pd] = (e << 1) | 1;    // node is dst -> sign +
    }
}

// Convert W[K][128] fp32 -> B-fragment-layout fp16 for mfma_f32_16x16x32_f16.
// blockIdx.y = layer; strides passed per weight type.
__global__ void k_wprepL(const float* __restrict__ W, _Float16* __restrict__ Wf,
                         int K, int wstride) {
    int l = blockIdx.y;
    const float* Wl = W + (size_t)l * wstride;
    _Float16* Wfl = Wf + (size_t)l * K * 128;
    int idx = blockIdx.x * 256 + threadIdx.x;
    if (idx >= K * 128) return;
    int j = idx & 7, lane = (idx >> 3) & 63, nt = (idx >> 9) & 7, kt = idx >> 12;
    int k = kt * 32 + (lane >> 4) * 8 + j;
    int n = nt * 16 + (lane & 15);
    Wfl[idx] = (_Float16)Wl[k * 128 + n];
}

__global__ void k_temb(const float* __restrict__ tv,
                       const float* __restrict__ W1, const float* __restrict__ b1,
                       const float* __restrict__ W2, const float* __restrict__ b2,
                       float* __restrict__ t_emb) {
    __shared__ float te[64];
    __shared__ float h1[128];
    int b = blockIdx.x;
    int tid = threadIdx.x;
    float tval = tv[b];
    if (tid < 32) {
        float fr = __expf((float)tid * (-logf(10000.f) / 31.f));
        float a = tval * fr;
        te[tid] = sinf(a);
        te[tid + 32] = cosf(a);
    }
    __syncthreads();
    float acc = b1[tid];
    for (int k = 0; k < 64; ++k) acc += te[k] * W1[k * 128 + tid];
    h1[tid] = silu_f(acc);
    __syncthreads();
    float acc2 = b2[tid];
    for (int k = 0; k < 128; ++k) acc2 += h1[k] * W2[k * 128 + tid];
    t_emb[b * 128 + tid] = acc2;
}

__global__ void k_embproj(const float* __restrict__ emb, const float* __restrict__ W,
                          const float* __restrict__ bias, float* __restrict__ outp) {
    int tid = threadIdx.x;       // 512 threads
    int a = tid >> 7, j = tid & 127;
    float acc = bias[j];
    for (int k = 0; k < 128; ++k) acc += emb[a * 128 + k] * W[k * 128 + j];
    outp[a * 128 + j] = acc;
}

__global__ void k_hinit(const int* __restrict__ at, const float* __restrict__ embp,
                        const float* __restrict__ temb, float* __restrict__ h,
                        _Float16* __restrict__ h16) {
    size_t idx4 = (size_t)blockIdx.x * 256 + threadIdx.x;   // over B*N*H/4
    size_t e0 = idx4 * 4;
    int j = (int)(e0 % H_);
    size_t bn = e0 / H_;
    int n = (int)(bn % N_);
    int b = (int)(bn / N_);
    int a = at[n];
    float4 ep = *(const float4*)(embp + a * H_ + j);
    float4 tv = *(const float4*)(temb + b * H_ + j);
    float4 r = make_float4(ep.x + tv.x, ep.y + tv.y, ep.z + tv.z, ep.w + tv.w);
    ((float4*)h)[idx4] = r;
    f16x4v o;
    o[0] = (_Float16)r.x; o[1] = (_Float16)r.y; o[2] = (_Float16)r.z; o[3] = (_Float16)r.w;
    *(f16x4v*)(h16 + e0) = o;
}

__global__ void k_xcopy(const float* __restrict__ x, float* __restrict__ xb) {
    int i = blockIdx.x * 256 + threadIdx.x;  // 480000 exact
    xb[i] = x[i];
}

// ---------------- MFMA GEMM cores (wave-local) ----------------
// Single row-tile (16 rows/wave):
template <int RS, int KT>
__device__ __forceinline__ void mfma_gemm(const _Float16* Asw, const _Float16* __restrict__ Wf,
                                          f32x4 (&acc)[8], int ml, int quad, int lane) {
    #pragma unroll
    for (int kt = 0; kt < KT; ++kt) {
        f16x8 a = *(const f16x8*)(Asw + ml * RS + kt * 32 + quad * 8);
        #pragma unroll
        for (int nt = 0; nt < 8; ++nt) {
            f16x8 b = *(const f16x8*)(Wf + (((kt * 8 + nt) * 64 + lane) * 8));
            acc[nt] = __builtin_amdgcn_mfma_f32_16x16x32_f16(a, b, acc[nt], 0, 0, 0);
        }
    }
}

// Two row-tiles (32 rows/wave) sharing each B fragment:
template <int RS, int KT>
__device__ __forceinline__ void mfma_gemm2(const _Float16* Asw, const _Float16* __restrict__ Wf,
                                           f32x4 (&acc)[2][8], int ml, int quad, int lane) {
    #pragma unroll
    for (int kt = 0; kt < KT; ++kt) {
        f16x8 a0 = *(const f16x8*)(Asw + ml * RS + kt * 32 + quad * 8);
        f16x8 a1 = *(const f16x8*)(Asw + (16 + ml) * RS + kt * 32 + quad * 8);
        #pragma unroll
        for (int nt = 0; nt < 8; ++nt) {
            f16x8 b = *(const f16x8*)(Wf + (((kt * 8 + nt) * 64 + lane) * 8));
            acc[0][nt] = __builtin_amdgcn_mfma_f32_16x16x32_f16(a0, b, acc[0][nt], 0, 0, 0);
            acc[1][nt] = __builtin_amdgcn_mfma_f32_16x16x32_f16(a1, b, acc[1][nt], 0, 0, 0);
        }
    }
}

// ---------------- fp32 tiled GEMM (k_out2 only) ----------------
template <int STRIDE, int K>
__device__ __forceinline__ void gemm_t(const float* As, const float* __restrict__ W,
                                       float (&acc)[4][8], int r4, int c) {
    const float4* Wv = (const float4*)W;
    #pragma unroll 2
    for (int k = 0; k < K; k += 4) {
        float a[4][4];
        #pragma unroll
        for (int i = 0; i < 4; ++i)
            *(float4*)a[i] = *(const float4*)(As + (r4 + i) * STRIDE + k);
        #pragma unroll
        for (int kk = 0; kk < 4; ++kk) {
            float4 w0 = Wv[(k + kk) * 32 + c * 2];
            float4 w1 = Wv[(k + kk) * 32 + c * 2 + 1];
            #pragma unroll
            for (int i = 0; i < 4; ++i) {
                float av = a[i][kk];
                acc[i][0] += av * w0.x; acc[i][1] += av * w0.y;
                acc[i][2] += av * w0.z; acc[i][3] += av * w0.w;
                acc[i][4] += av * w1.x; acc[i][5] += av * w1.y;
                acc[i][6] += av * w1.z; acc[i][7] += av * w1.w;
            }
        }
    }
}

__device__ __forceinline__ void bias_init(float (&acc)[4][8], const float* __restrict__ bias, int c) {
    float4 b0 = ((const float4*)bias)[c * 2];
    float4 b1 = ((const float4*)bias)[c * 2 + 1];
    #pragma unroll
    for (int i = 0; i < 4; ++i) {
        acc[i][0] = b0.x; acc[i][1] = b0.y; acc[i][2] = b0.z; acc[i][3] = b0.w;
        acc[i][4] = b1.x; acc[i][5] = b1.y; acc[i][6] = b1.z; acc[i][7] = b1.w;
    }
}

// ---------------- per-layer kernels ----------------

// 64 edges/block, 128 threads = 2 waves x 32 rows (2-row-tile MFMA: each
// B-frag load feeds 2 MFMAs -> per-edge weight L2 traffic halves vs R8).
// Fully wave-local (NO __syncthreads); split-K restage of h_dst over h_src.
// Batch-per-XCD swizzle: b = blockIdx.x & 7 (E_/EPB = 625 chunks exactly).
__global__ __launch_bounds__(128, 4) void k_edge_mfma(
    const _Float16* __restrict__ h16, const float* __restrict__ xcur,
    const int* __restrict__ bond,
    const float* __restrict__ Wm1, const float* __restrict__ bm1,
    const _Float16* __restrict__ Wm1f,
    const float* __restrict__ bm2, const _Float16* __restrict__ Wm2f,
    const float* __restrict__ bc1, const _Float16* __restrict__ Wc1f,
    const float* __restrict__ Wc2,
    _Float16* __restrict__ m16, float* __restrict__ cw_out) {
    __shared__ _Float16 As[EPB * MRS];   // 17408 B
    __shared__ float ds_s[EPB];
    int tid = threadIdx.x;
    int b = blockIdx.x & 7;              // batch -> XCD locality
    int e0 = (blockIdx.x >> 3) * EPB;    // chunk within batch (0..624)
    size_t be0 = (size_t)b * E_ + e0;

    int el = tid >> 1, q = tid & 1;      // 2 threads/row; rows are wave-own
    int2 sd = ((const int2*)bond)[e0 + el];
    int s = sd.x, d = sd.y;
    if (q == 0) {
        const float* xs = xcur + ((size_t)b * N_ + s) * 3;
        const float* xd = xcur + ((size_t)b * N_ + d) * 3;
        float dx = xd[0] - xs[0], dy = xd[1] - xs[1], dz = xd[2] - xs[2];
        ds_s[el] = sqrtf(dx * dx + dy * dy + dz * dz);
    }
    // stage h_src (cols q*64 .. q*64+63)
    {
        const _Float16* hs = h16 + ((size_t)b * N_ + s) * H_;
        #pragma unroll
        for (int j = 0; j < 8; ++j)
            *(f16x8*)(As + el * MRS + q * 64 + j * 8) = *(const f16x8*)(hs + q * 64 + j * 8);
    }
    WFENCE;

    int lane = tid & 63, w = tid >> 6;   // w in {0,1}; wave owns rows w*32..w*32+31
    int ml = lane & 15, quad = lane >> 4;
    _Float16* Asw = As + w * 32 * MRS;
    const float* wd = Wm1 + 256 * H_;

    f32x4 acc[2][8];
    // acc = bm1 + dist*wd
    #pragma unroll
    for (int nt = 0; nt < 8; ++nt) {
        int col = nt * 16 + ml;
        float bb = bm1[col];
        float ww = wd[col];
        #pragma unroll
        for (int rt = 0; rt < 2; ++rt)
            #pragma unroll
            for (int r = 0; r < 4; ++r)
                acc[rt][nt][r] = bb + ds_s[w * 32 + rt * 16 + quad * 4 + r] * ww;
    }
    mfma_gemm2<MRS, 4>(Asw, Wm1f, acc, ml, quad, lane);              // + h_s @ Wm1[0:128]
    WFENCE;
    // restage h_dst over the same LDS (wave-own rows; in-order DS pipe)
    {
        const _Float16* hd = h16 + ((size_t)b * N_ + d) * H_;
        #pragma unroll
        for (int j = 0; j < 8; ++j)
            *(f16x8*)(As + el * MRS + q * 64 + j * 8) = *(const f16x8*)(hd + q * 64 + j * 8);
    }
    WFENCE;
    mfma_gemm2<MRS, 4>(Asw, Wm1f + 4 * 8 * 64 * 8, acc, ml, quad, lane);  // + h_d @ Wm1[128:256]
    WFENCE;
    // repack m1 = silu(acc) -> As (wave-own rows)
    #pragma unroll
    for (int rt = 0; rt < 2; ++rt)
        #pragma unroll
        for (int nt = 0; nt < 8; ++nt)
            #pragma unroll
            for (int r = 0; r < 4; ++r)
                Asw[(rt * 16 + quad * 4 + r) * MRS + nt * 16 + ml] = (_Float16)silu_f(acc[rt][nt][r]);
    WFENCE;

    // ---- GEMM2: m = silu(m1 @ Wm2 + bm2)
    #pragma unroll
    for (int nt = 0; nt < 8; ++nt) {
        float bb = bm2[nt * 16 + ml];
        #pragma unroll
        for (int rt = 0; rt < 2; ++rt)
            #pragma unroll
            for (int r = 0; r < 4; ++r) acc[rt][nt][r] = bb;
    }
    mfma_gemm2<MRS, 4>(Asw, Wm2f, acc, ml, quad, lane);
    WFENCE;
    // repack m -> As (overwrites m1; this wave's GEMM2 reads are done)
    #pragma unroll
    for (int rt = 0; rt < 2; ++rt)
        #pragma unroll
        for (int nt = 0; nt < 8; ++nt)
            #pragma unroll
            for (int r = 0; r < 4; ++r)
                Asw[(rt * 16 + quad * 4 + r) * MRS + nt * 16 + ml] = (_Float16)silu_f(acc[rt][nt][r]);
    WFENCE;
    // vectorized coalesced m16 store from LDS (wave-own rows)
    #pragma unroll
    for (int j = 0; j < 8; ++j)
        *(f16x8*)(m16 + (be0 + el) * H_ + q * 64 + j * 8) =
            *(const f16x8*)(As + el * MRS + q * 64 + j * 8);

    // ---- GEMM3: cw = silu(m @ Wc1 + bc1) @ Wc2
    #pragma unroll
    for (int nt = 0; nt < 8; ++nt) {
        float bb = bc1[nt * 16 + ml];
        #pragma unroll
        for (int rt = 0; rt < 2; ++rt)
            #pragma unroll
            for (int r = 0; r < 4; ++r) acc[rt][nt][r] = bb;
    }
    mfma_gemm2<MRS, 4>(Asw, Wc1f, acc, ml, quad, lane);
    float part[2][4] = {{0.f, 0.f, 0.f, 0.f}, {0.f, 0.f, 0.f, 0.f}};
    #pragma unroll
    for (int nt = 0; nt < 8; ++nt) {
        float wv = Wc2[nt * 16 + ml];
        #pragma unroll
        for (int rt = 0; rt < 2; ++rt)
            #pragma unroll
            for (int r = 0; r < 4; ++r) part[rt][r] += silu_f(acc[rt][nt][r]) * wv;
    }
    #pragma unroll
    for (int off = 1; off < 16; off <<= 1)
        #pragma unroll
        for (int rt = 0; rt < 2; ++rt)
            #pragma unroll
            for (int r = 0; r < 4; ++r) part[rt][r] += __shfl_xor(part[rt][r], off, 64);
    if (ml == 0) {
        #pragma unroll
        for (int rt = 0; rt < 2; ++rt)
            #pragma unroll
            for (int r = 0; r < 4; ++r)
                cw_out[be0 + w * 32 + rt * 16 + quad * 4 + r] = part[rt][r];
    }
}

__global__ void k_coord(const float* __restrict__ xcur, float* __restrict__ xnext,
                        const float* __restrict__ cw, const int* __restrict__ bond,
                        const int* __restrict__ indptr, const int* __restrict__ adj) {
    int idx = blockIdx.x * 256 + threadIdx.x;   // B*N exact
    int b = idx / N_;
    int n = idx - b * N_;
    const float* xb = xcur + (size_t)b * N_ * 3;
    int p0 = indptr[n], p1 = indptr[n + 1];
    float ax = 0.f, ay = 0.f, az = 0.f;
    for (int p = p0; p < p1; ++p) {
        int a = adj[p];
        int e = a >> 1;
        float sgn = (a & 1) ? 1.f : -1.f;
        int s = bond[2 * e], d = bond[2 * e + 1];
        float dx = xb[d * 3 + 0] - xb[s * 3 + 0];
        float dy = xb[d * 3 + 1] - xb[s * 3 + 1];
        float dz = xb[d * 3 + 2] - xb[s * 3 + 2];
        float dist = sqrtf(dx * dx + dy * dy + dz * dz);
        float w = cw[(size_t)b * E_ + e] * sgn * __builtin_amdgcn_rcpf(dist + 1e-8f);
        ax += dx * w; ay += dy * w; az += dz * w;
    }
    float rcnt = __builtin_amdgcn_rcpf((float)max(p1 - p0, 1));
    xnext[(size_t)idx * 3 + 0] = xb[n * 3 + 0] + ax * rcnt;
    xnext[(size_t)idx * 3 + 1] = xb[n * 3 + 1] + ay * rcnt;
    xnext[(size_t)idx * 3 + 2] = xb[n * 3 + 2] + az * rcnt;
}

// 64 nodes/block, wave-local (NO __syncthreads):
// u = silu(h@Wn1a + agg@Wn1b + bn1); h += u@Wn2 + bn2
__global__ __launch_bounds__(256, 5) void k_node_mfma(
    float* __restrict__ h, _Float16* __restrict__ h16,
    const _Float16* __restrict__ m16,
    const int* __restrict__ indptr, const int* __restrict__ adj,
    const float* __restrict__ bn1, const _Float16* __restrict__ Wn1f,
    const float* __restrict__ bn2, const _Float16* __restrict__ Wn2f) {
    __shared__ _Float16 As[NPB * MRS];   // 17408 B
    int tid = threadIdx.x;
    int el = tid >> 2, q = tid & 3;
    int be = blockIdx.x * NPB + el;   // b*N + n
    int b = be / N_, n = be - b * N_;
    // stage h tile (fp16, wave-own rows)
    {
        const _Float16* hr = h16 + (size_t)be * H_;
        #pragma unroll
        for (int j = 0; j < 4; ++j)
            *(f16x8*)(As + el * MRS + q * 32 + j * 8) = *(const f16x8*)(hr + q * 32 + j * 8);
    }
    WFENCE;

    int lane = tid & 63, w = tid >> 6;
    int ml = lane & 15, quad = lane >> 4;
    _Float16* Asw = As + w * 16 * MRS;
    size_t be0 = (size_t)blockIdx.x * NPB;

    f32x4 acc[8];
    #pragma unroll
    for (int nt = 0; nt < 8; ++nt) {
        float bb = bn1[nt * 16 + ml];
        #pragma unroll
        for (int r = 0; r < 4; ++r) acc[nt][r] = bb;
    }
    mfma_gemm<MRS, 4>(Asw, Wn1f, acc, ml, quad, lane);     // + h @ Wn1a
    WFENCE;
    // agg gather -> As (overwrites h tile; wave-own rows; 4 threads/row)
    {
        float ag[4][8];
        #pragma unroll
        for (int j = 0; j < 4; ++j)
            #pragma unroll
            for (int i = 0; i < 8; ++i) ag[j][i] = 0.f;
        int p0 = indptr[n], p1 = indptr[n + 1];
        for (int p = p0; p < p1; ++p) {
            int e = adj[p] >> 1;
            const _Float16* mp = m16 + ((size_t)b * E_ + e) * H_;
            #pragma unroll
            for (int j = 0; j < 4; ++j) {
                f16x8 v = *(const f16x8*)(mp + q * 32 + j * 8);
                #pragma unroll
                for (int i = 0; i < 8; ++i) ag[j][i] += (float)v[i];
            }
        }
        #pragma unroll
        for (int j = 0; j < 4; ++j) {
            f16x8 o;
            #pragma unroll
            for (int i = 0; i < 8; ++i) o[i] = (_Float16)ag[j][i];
            *(f16x8*)(As + el * MRS + q * 32 + j * 8) = o;
        }
    }
    WFENCE;
    mfma_gemm<MRS, 4>(Asw, Wn1f + 4 * 8 * 64 * 8, acc, ml, quad, lane);  // + agg @ Wn1b
    WFENCE;
    // u -> As (wave-own rows)
    #pragma unroll
    for (int nt = 0; nt < 8; ++nt)
        #pragma unroll
        for (int r = 0; r < 4; ++r)
            Asw[(quad * 4 + r) * MRS + nt * 16 + ml] = (_Float16)silu_f(acc[nt][r]);
    WFENCE;
    f32x4 acc2[8];
    #pragma unroll
    for (int nt = 0; nt < 8; ++nt) {
        float bb = bn2[nt * 16 + ml];
        #pragma unroll
        for (int r = 0; r < 4; ++r) acc2[nt][r] = bb;
    }
    mfma_gemm<MRS, 4>(Asw, Wn2f, acc2, ml, quad, lane);
    // residual (fp32 h) + writeback h and h16
    #pragma unroll
    for (int nt = 0; nt < 8; ++nt)
        #pragma unroll
        for (int r = 0; r < 4; ++r) {
            int row = w * 16 + quad * 4 + r;
            size_t g = (size_t)(be0 + row) * H_ + nt * 16 + ml;
            float v = h[g] + acc2[nt][r];
            h[g] = v;
            h16[g] = (_Float16)v;
        }
}

// out = silu(h@Wo1+bo1)@Wo2 + bo2 + (xfin - xorig)  (cross-wave reduce: keep barriers)
__global__ __launch_bounds__(256) void k_out2(
    const float* __restrict__ h, const float* __restrict__ xfin, const float* __restrict__ xorig,
    const float* __restrict__ Wo1, const float* __restrict__ bo1,
    const float* __restrict__ Wo2, const float* __restrict__ bo2,
    float* __restrict__ out) {
    __shared__ float As[64 * TS];
    __shared__ float red[64 * 48];
    int tid = threadIdx.x;
    {
        int nl = tid >> 2, q = tid & 3;
        size_t row = (size_t)blockIdx.x * 64 + nl;
        const float4* hr = (const float4*)(h + row * H_);
        #pragma unroll
        for (int j = 0; j < 8; ++j) {
            int f4 = j * 4 + q;
            *(float4*)(As + nl * TS + f4 * 4) = hr[f4];
        }
    }
    __syncthreads();
    int r4 = (tid >> 4) * 4, c = tid & 15;
    float acc[4][8];
    bias_init(acc, bo1, c);
    gemm_t<TS, 128>(As, Wo1, acc, r4, c);
    #pragma unroll
    for (int i = 0; i < 4; ++i) {
        float p0 = 0.f, p1 = 0.f, p2 = 0.f;
        #pragma unroll
        for (int j = 0; j < 8; ++j) {
            float u = silu_f(acc[i][j]);
            int col = c * 8 + j;
            p0 += u * Wo2[col * 3 + 0];
            p1 += u * Wo2[col * 3 + 1];
            p2 += u * Wo2[col * 3 + 2];
        }
        red[(r4 + i) * 48 + c * 3 + 0] = p0;
        red[(r4 + i) * 48 + c * 3 + 1] = p1;
        red[(r4 + i) * 48 + c * 3 + 2] = p2;
    }
    __syncthreads();
    if (tid < 192) {
        int row = tid / 3, jj = tid - row * 3;
        float s = 0.f;
        #pragma unroll
        for (int cc = 0; cc < 16; ++cc) s += red[row * 48 + cc * 3 + jj];
        size_t grow = (size_t)blockIdx.x * 64 + row;
        out[grow * 3 + jj] = s + bo2[jj] + xfin[grow * 3 + jj] - xorig[grow * 3 + jj];
    }
}

// ---------------- launcher ----------------

extern "C" void kernel_launch(void* const* d_in, const int* in_sizes, int n_in,
                              void* d_out, int out_size, void* d_ws, size_t ws_size,
                              hipStream_t stream) {
    const float* x = (const float*)d_in[0];
    const float* t = (const float*)d_in[1];
    const int* atom_types = (const int*)d_in[2];
    const int* bond = (const int*)d_in[3];
    const float* emb_table = (const float*)d_in[4];
    const float* W_t1 = (const float*)d_in[5];
    const float* b_t1 = (const float*)d_in[6];
    const float* W_t2 = (const float*)d_in[7];
    const float* b_t2 = (const float*)d_in[8];
    const float* W_node = (const float*)d_in[9];
    const float* b_node = (const float*)d_in[10];
    const float* Wm1 = (const float*)d_in[11];
    const float* bm1 = (const float*)d_in[12];
    const float* Wm2 = (const float*)d_in[13];
    const float* bm2 = (const float*)d_in[14];
    const float* Wn1 = (const float*)d_in[15];
    const float* bn1 = (const float*)d_in[16];
    const float* Wn2 = (const float*)d_in[17];
    const float* bn2 = (const float*)d_in[18];
    const float* Wc1 = (const float*)d_in[19];
    const float* bc1 = (const float*)d_in[20];
    const float* Wc2 = (const float*)d_in[21];
    const float* W_o1 = (const float*)d_in[22];
    const float* b_o1 = (const float*)d_in[23];
    const float* W_o2 = (const float*)d_in[24];
    const float* b_o2 = (const float*)d_in[25];
    float* out = (float*)d_out;

    char* p = (char*)d_ws;
    auto alloc = [&](size_t bytes) -> void* {
        void* r = (void*)p;
        p += (bytes + 255) & ~(size_t)255;
        return r;
    };
    // ~211 MB total (R1's 252 MB layout fit; R2's 415 MB overflowed)
    float* t_emb = (float*)alloc((size_t)B_ * H_ * 4);
    float* emb_proj = (float*)alloc((size_t)A_ * H_ * 4);
    int* deg = (int*)alloc((size_t)N_ * 4);
    int* indptr = (int*)alloc((size_t)(N_ + 1) * 4);
    int* cursor = (int*)alloc((size_t)N_ * 4);
    int* adj = (int*)alloc((size_t)2 * E_ * 4);
    float* xb0 = (float*)alloc((size_t)B_ * N_ * 3 * 4);
    float* xb1 = (float*)alloc((size_t)B_ * N_ * 3 * 4);
    float* cw = (float*)alloc((size_t)B_ * E_ * 4);
    float* h = (float*)alloc((size_t)B_ * N_ * H_ * 4);
    _Float16* h16 = (_Float16*)alloc((size_t)B_ * N_ * H_ * 2);
    _Float16* m16 = (_Float16*)alloc((size_t)B_ * E_ * H_ * 2);
    _Float16* Wm1f = (_Float16*)alloc((size_t)L_ * 256 * H_ * 2);
    _Float16* Wm2f = (_Float16*)alloc((size_t)L_ * H_ * H_ * 2);
    _Float16* Wc1f = (_Float16*)alloc((size_t)L_ * H_ * H_ * 2);
    _Float16* Wn1f = (_Float16*)alloc((size_t)L_ * 256 * H_ * 2);
    _Float16* Wn2f = (_Float16*)alloc((size_t)L_ * H_ * H_ * 2);

    k_zero<<<(N_ + 255) / 256, 256, 0, stream>>>(deg, cursor);
    k_deg<<<(E_ + 255) / 256, 256, 0, stream>>>(bond, deg);
    k_scan<<<1, 1024, 0, stream>>>(deg, indptr);
    k_fill<<<(E_ + 255) / 256, 256, 0, stream>>>(bond, indptr, cursor, adj);
    k_temb<<<B_, 128, 0, stream>>>(t, W_t1, b_t1, W_t2, b_t2, t_emb);
    k_embproj<<<1, 512, 0, stream>>>(emb_table, W_node, b_node, emb_proj);
    k_hinit<<<(B_ * N_ * H_ / 4) / 256, 256, 0, stream>>>(atom_types, emb_proj, t_emb, h, h16);
    k_xcopy<<<(B_ * N_ * 3) / 256, 256, 0, stream>>>(x, xb0);
    // weight prep: one launch per weight type, layer via blockIdx.y
    k_wprepL<<<dim3(128, L_), 256, 0, stream>>>(Wm1, Wm1f, 256, 257 * H_);
    k_wprepL<<<dim3(64, L_), 256, 0, stream>>>(Wm2, Wm2f, 128, H_ * H_);
    k_wprepL<<<dim3(64, L_), 256, 0, stream>>>(Wc1, Wc1f, 128, H_ * H_);
    k_wprepL<<<dim3(128, L_), 256, 0, stream>>>(Wn1, Wn1f, 256, 2 * H_ * H_);
    k_wprepL<<<dim3(64, L_), 256, 0, stream>>>(Wn2, Wn2f, 128, H_ * H_);

    float* xc = xb0;
    float* xn = xb1;
    for (int l = 0; l < L_; ++l) {
        k_edge_mfma<<<(B_ * E_) / EPB, 128, 0, stream>>>(
            h16, xc, bond,
            Wm1 + (size_t)l * 257 * H_, bm1 + l * H_, Wm1f + (size_t)l * 256 * H_,
            bm2 + l * H_, Wm2f + (size_t)l * H_ * H_,
            bc1 + l * H_, Wc1f + (size_t)l * H_ * H_,
            Wc2 + (size_t)l * H_, m16, cw);
        k_coord<<<(B_ * N_) / 256, 256, 0, stream>>>(xc, xn, cw, bond, indptr, adj);
        k_node_mfma<<<(B_ * N_) / NPB, 256, 0, stream>>>(
            h, h16, m16, indptr, adj,
            bn1 + l * H_, Wn1f + (size_t)l * 256 * H_,
            bn2 + l * H_, Wn2f + (size_t)l * H_ * H_);
        float* tmp = xc; xc = xn; xn = tmp;
    }
    k_out2<<<(B_ * N_) / 64, 256, 0, stream>>>(h, xc, x, W_o1, b_o1, W_o2, b_o2, out);
}